// Round 7
// baseline (280.625 us; speedup 1.0000x reference)
//
#include <hip/hip_runtime.h>
#include <hip/hip_bf16.h>
#include <math.h>

#define EPS 1e-5f
#define ST 816                 // padded Bmap row stride (elems)
#define PLANE (816 * 808)      // padded plane elems

typedef _Float16 f16x8 __attribute__((ext_vector_type(8)));
typedef float f32x4 __attribute__((ext_vector_type(4)));

__device__ __forceinline__ float elu_f(float x) {
    return x > 0.f ? x : __expf(x) - 1.f;
}

// ---------------- Kernel 1: e = elu(z @ W_emb^T + b_emb) ----------------
__global__ __launch_bounds__(256) void kembed(const float* __restrict__ z0,
                                              const float* __restrict__ z1,
                                              const float* __restrict__ Wemb,
                                              const float* __restrict__ bemb,
                                              float* __restrict__ e0,
                                              float* __restrict__ e1) {
    __shared__ float4 zs4[2048];  // 8 rows x 1024 floats
    int src = blockIdx.x & 1;
    int rowbase = (blockIdx.x >> 1) * 8;
    const float* z = src ? z1 : z0;
    float* e = src ? e1 : e0;
    const float4* zrow4 = reinterpret_cast<const float4*>(z + rowbase * 1024);
    for (int idx = threadIdx.x; idx < 2048; idx += 256) zs4[idx] = zrow4[idx];
    __syncthreads();
    int t = threadIdx.x;
    if (t < 200) {
        int d = t % 100;
        int half = t / 100;
        const float4* w4 = reinterpret_cast<const float4*>(Wemb + d * 1024);
        float acc[4] = {0.f, 0.f, 0.f, 0.f};
        for (int k = 0; k < 256; k++) {
            float4 w = w4[k];
#pragma unroll
            for (int r = 0; r < 4; r++) {
                float4 zv = zs4[(half * 4 + r) * 256 + k];
                acc[r] = fmaf(w.x, zv.x, acc[r]);
                acc[r] = fmaf(w.y, zv.y, acc[r]);
                acc[r] = fmaf(w.z, zv.z, acc[r]);
                acc[r] = fmaf(w.w, zv.w, acc[r]);
            }
        }
        float be = bemb[d];
#pragma unroll
        for (int r = 0; r < 4; r++) {
            e[(rowbase + half * 4 + r) * 100 + d] = elu_f(acc[r] + be);
        }
    }
}

// ---------------- Prep: pack W1 as fp16 B-fragments, d-interleaved K ----------------
__global__ __launch_bounds__(256) void kprepW(const float* __restrict__ W1,
                                              unsigned short* __restrict__ Bh) {
    int idx = blockIdx.x * 256 + threadIdx.x;
    if (idx >= 14336) return;
    int i = idx & 7;
    int lane = (idx >> 3) & 63;
    int hf = (idx >> 9) & 3;
    int ks = idx >> 11;              // 0..6
    int h = hf * 16 + (lane & 15);
    int k = ks * 32 + (lane >> 4) * 8 + i;
    int d = k >> 1;
    int term = k & 1;
    float val = (d < 100 && h < 50) ? W1[h * 200 + term * 100 + d] : 0.f;
    _Float16 hv = (_Float16)val;
    Bh[idx] = __builtin_bit_cast(unsigned short, hv);
}

// ---------------- kzero: zero the halo borders of padded Bmap ----------------
__global__ __launch_bounds__(256) void kzero(unsigned short* __restrict__ Bmap) {
    const int per = 4896 + 12800;
    int idx = blockIdx.x * 256 + threadIdx.x;
    if (idx >= 50 * per) return;
    int h = idx / per, q = idx % per;
    int row, col;
    if (q < 4896) {
        int rr = q / 816;
        col = q - rr * 816;
        row = rr < 3 ? rr : 800 + rr;
    } else {
        int q2 = q - 4896;
        row = 3 + (q2 >> 4);
        int m = q2 & 15;
        col = m < 8 ? m : 800 + m;
    }
    Bmap[(size_t)h * PLANE + (size_t)row * ST + col] = 0;
}

// ---------------- Kernel 2: interaction GEMM via MFMA (fp16) ----------------
// grid (100,13), block 256 = 4 waves. Tile 8 i x 64 j. Wave owns 2 i (fl), 4 j-frags.
__global__ __launch_bounds__(256) void kinter(const float* __restrict__ e0,
                                              const float* __restrict__ e1,
                                              const unsigned short* __restrict__ Bh,
                                              const float* __restrict__ b1,
                                              const float* __restrict__ g1,
                                              const float* __restrict__ bb1,
                                              const float* __restrict__ m1,
                                              const float* __restrict__ v1,
                                              __hip_bfloat16* __restrict__ Bmap) {
    __shared__ float e0s[8][116];
    __shared__ float e1s[64][116];
    int i0 = blockIdx.x * 8, j0 = blockIdx.y * 64;
    int tid = threadIdx.x;
    for (int idx = tid; idx < 72 * 116; idx += 256) {
        int r = idx / 116, c = idx % 116;
        float v = 0.f;
        if (c < 100) {
            if (r < 8) v = e0[(i0 + r) * 100 + c];
            else if (j0 + r - 8 < 800) v = e1[(j0 + r - 8) * 100 + c];
        }
        if (r < 8) e0s[r][c] = v;
        else e1s[r - 8][c] = v;
    }
    __syncthreads();

    int lane = tid & 63;
    int wid = tid >> 6;
    int g = lane >> 4;        // k-subchunk 0..3
    int jrow = lane & 15;     // A-row = j within frag

    f32x4 acc[2][4][4] = {};  // [fl][jf][hf]

    for (int ks = 0; ks < 7; ++ks) {
        f16x8 b[4];
#pragma unroll
        for (int hf = 0; hf < 4; ++hf) {
            int fidx = ((ks * 4 + hf) * 64 + lane) * 8;
            b[hf] = __builtin_bit_cast(f16x8, *(const uint4*)(Bh + fidx));
        }
        int d0 = ks * 16 + g * 4;
        float4 x0v[2];
        x0v[0] = *(const float4*)&e0s[wid * 2 + 0][d0];
        x0v[1] = *(const float4*)&e0s[wid * 2 + 1][d0];
#pragma unroll
        for (int jf = 0; jf < 4; ++jf) {
            float4 x1 = *(const float4*)&e1s[jf * 16 + jrow][d0];
#pragma unroll
            for (int fl = 0; fl < 2; ++fl) {
                float4 x0 = x0v[fl];
                unsigned int u0 = __builtin_bit_cast(unsigned int,
                    __builtin_amdgcn_cvt_pkrtz(fabsf(x0.x - x1.x), x0.x * x1.x));
                unsigned int u1 = __builtin_bit_cast(unsigned int,
                    __builtin_amdgcn_cvt_pkrtz(fabsf(x0.y - x1.y), x0.y * x1.y));
                unsigned int u2 = __builtin_bit_cast(unsigned int,
                    __builtin_amdgcn_cvt_pkrtz(fabsf(x0.z - x1.z), x0.z * x1.z));
                unsigned int u3 = __builtin_bit_cast(unsigned int,
                    __builtin_amdgcn_cvt_pkrtz(fabsf(x0.w - x1.w), x0.w * x1.w));
                uint4 au = {u0, u1, u2, u3};
                f16x8 a = __builtin_bit_cast(f16x8, au);
#pragma unroll
                for (int hf = 0; hf < 4; ++hf) {
                    acc[fl][jf][hf] = __builtin_amdgcn_mfma_f32_16x16x32_f16(
                        a, b[hf], acc[fl][jf][hf], 0, 0, 0);
                }
            }
        }
    }

    // epilogue: D[row=j][col=h]; lane (g,hl): rows j = jf*16 + g*4 + r, col h = hf*16+hl
    int hl = lane & 15;
#pragma unroll
    for (int hf = 0; hf < 4; ++hf) {
        int h = hf * 16 + hl;
        bool ok = h < 50;
        int hc = ok ? h : 0;
        float bnb = b1[hc];
        float sc = g1[hc] * rsqrtf(v1[hc] + EPS);
        float off = bb1[hc] - m1[hc] * sc;
#pragma unroll
        for (int fl = 0; fl < 2; ++fl) {
            int i = i0 + wid * 2 + fl;
#pragma unroll
            for (int jf = 0; jf < 4; ++jf) {
                int j = j0 + jf * 16 + g * 4;
                f32x4 a = acc[fl][jf][hf];
                unsigned short o[4];
#pragma unroll
                for (int r = 0; r < 4; ++r) {
                    float x = a[r] + bnb;
                    x = elu_f(x);
                    x = fmaf(x, sc, off);
                    x = elu_f(x);
                    o[r] = __builtin_bit_cast(unsigned short, (__bf16)x);
                }
                if (ok && j < 800) {
                    *(ushort4*)&Bmap[(size_t)h * PLANE + (size_t)(i + 3) * ST + (j + 8)] =
                        *(ushort4*)o;
                }
            }
        }
    }
}

// ---------------- Kernel 3: 7x7 conv, 64x64 tile, 256 thr, 4x4 out/thread ----------------
// grid (13,13,10). tile[70][84]: b128-only LDS access (conflict-free); scalar W2 loads.
__global__ __launch_bounds__(256) void kconv(const __hip_bfloat16* __restrict__ Bmap,
                                             const float* __restrict__ W2,
                                             float* __restrict__ Cpart) {
    __shared__ float tile[70][84];
    int bx = blockIdx.x, by = blockIdx.y, zc = blockIdx.z;
    int h0 = zc * 5;
    int tid = threadIdx.x;
    int lx = tid & 15, ly = tid >> 4;     // 16 x 16 threads
    float acc[4][4] = {};
    for (int hh = 0; hh < 5; ++hh) {
        int h = h0 + hh;
        __syncthreads();
        const __hip_bfloat16* plane = Bmap + (size_t)h * PLANE;
        // stage 70 rows x 80 cols (10 x uint4 of 8 bf16 per row), aligned, no branches
        for (int u = tid; u < 700; u += 256) {
            int r = u / 10, k = u - r * 10;
            uint4 v = *reinterpret_cast<const uint4*>(
                plane + (size_t)(64 * by + r) * ST + 64 * bx + 8 * k);
            float f[8];
            f[0] = __uint_as_float(v.x << 16);
            f[1] = __uint_as_float(v.x & 0xFFFF0000u);
            f[2] = __uint_as_float(v.y << 16);
            f[3] = __uint_as_float(v.y & 0xFFFF0000u);
            f[4] = __uint_as_float(v.z << 16);
            f[5] = __uint_as_float(v.z & 0xFFFF0000u);
            f[6] = __uint_as_float(v.w << 16);
            f[7] = __uint_as_float(v.w & 0xFFFF0000u);
            *(float4*)&tile[r][8 * k] = *(float4*)&f[0];
            *(float4*)&tile[r][8 * k + 4] = *(float4*)&f[4];
        }
        __syncthreads();
        const float* wp = W2 + h * 49;   // block-uniform -> scalar loads
#pragma unroll
        for (int r = 0; r < 10; ++r) {
            float w[12];
            *(float4*)&w[0] = *(const float4*)&tile[4 * ly + r][4 * lx + 4];
            *(float4*)&w[4] = *(const float4*)&tile[4 * ly + r][4 * lx + 8];
            *(float4*)&w[8] = *(const float4*)&tile[4 * ly + r][4 * lx + 12];
#pragma unroll
            for (int rr = 0; rr < 4; ++rr) {
                int di = r - rr;
                if (di < 0 || di > 6) continue;
#pragma unroll
                for (int dj = 0; dj < 7; ++dj) {
                    float wt = wp[di * 7 + dj];
#pragma unroll
                    for (int cc = 0; cc < 4; ++cc)
                        acc[rr][cc] = fmaf(w[cc + dj + 1], wt, acc[rr][cc]);
                }
            }
        }
    }
    int j = 64 * bx + 4 * lx;
    if (j < 800) {
#pragma unroll
        for (int rr = 0; rr < 4; ++rr) {
            int i = 64 * by + 4 * ly + rr;
            if (i < 800)
                *(float4*)&Cpart[(size_t)zc * 640000 + (size_t)i * 800 + j] =
                    *(float4*)acc[rr];
        }
    }
}

// ---------------- Kernel 3b: reduce partials + bias + bn2 ----------------
__global__ __launch_bounds__(256) void kreduce(const float* __restrict__ Cpart,
                                               const float* __restrict__ b2,
                                               const float* __restrict__ g2,
                                               const float* __restrict__ bb2,
                                               const float* __restrict__ m2,
                                               const float* __restrict__ v2,
                                               float* __restrict__ C) {
    int idx = blockIdx.x * 256 + threadIdx.x;
    if (idx >= 160000) return;
    float s2 = g2[0] * rsqrtf(v2[0] + EPS);
    float t2 = bb2[0] - m2[0] * s2;
    float bias = b2[0];
    float4 s = ((const float4*)Cpart)[idx];
#pragma unroll
    for (int z = 1; z < 10; z++) {
        float4 p = ((const float4*)(Cpart + (size_t)z * 640000))[idx];
        s.x += p.x; s.y += p.y; s.z += p.z; s.w += p.w;
    }
    s.x = (s.x + bias) * s2 + t2;
    s.y = (s.y + bias) * s2 + t2;
    s.z = (s.z + bias) * s2 + t2;
    s.w = (s.w + bias) * s2 + t2;
    ((float4*)C)[idx] = s;
}

// ---------------- Kernel 4: 9x9/9 maxpool with pad 4 -> yhat (89x89) ----------------
__global__ __launch_bounds__(256) void kpool(const float* __restrict__ C,
                                             float* __restrict__ yhat) {
    int idx = blockIdx.x * 256 + threadIdx.x;
    if (idx >= 89 * 89) return;
    int oy = idx / 89, ox = idx % 89;
    float mx = -INFINITY;
    int y0 = oy * 9 - 4, x0 = ox * 9 - 4;
    for (int dy = 0; dy < 9; dy++) {
        int y = y0 + dy;
        if (y < 0 || y >= 800) continue;
        for (int dx = 0; dx < 9; dx++) {
            int x = x0 + dx;
            if (x < 0 || x >= 800) continue;
            mx = fmaxf(mx, C[y * 800 + x]);
        }
    }
    yhat[idx] = mx;
}

// ---------------- Kernel 5: mean/var -> Q -> phat -> gelu ----------------
__global__ __launch_bounds__(256) void kfinal(const float* __restrict__ yhat,
                                              const float* __restrict__ gamma,
                                              float* __restrict__ out) {
    const int N = 89 * 89;
    __shared__ float sA[4], sB[4];
    int tid = threadIdx.x;
    int wid = tid >> 6, lane = tid & 63;
    float s = 0.f, ss = 0.f;
    for (int i = tid; i < N; i += 256) {
        float y = yhat[i];
        s += y;
        ss = fmaf(y, y, ss);
    }
    for (int off = 32; off; off >>= 1) {
        s += __shfl_down(s, off);
        ss += __shfl_down(ss, off);
    }
    if (lane == 0) { sA[wid] = s; sB[wid] = ss; }
    __syncthreads();
    float S = sA[0] + sA[1] + sA[2] + sA[3];
    float SS = sB[0] + sB[1] + sB[2] + sB[3];
    float mu = S / (float)N;
    float var = (SS - S * S / (float)N) / (float)(N - 1);
    float thr = mu + gamma[0] * var;
    __syncthreads();
    float q = 0.f, c = 0.f;
    for (int i = tid; i < N; i += 256) {
        float d = yhat[i] - thr;
        if (d > 0.f) { q += d; c += 1.f; }
    }
    for (int off = 32; off; off >>= 1) {
        q += __shfl_down(q, off);
        c += __shfl_down(c, off);
    }
    if (lane == 0) { sA[wid] = q; sB[wid] = c; }
    __syncthreads();
    if (tid == 0) {
        float Q = sA[0] + sA[1] + sA[2] + sA[3];
        float Cnt = sB[0] + sB[1] + sB[2] + sB[3];
        float phat = Q / (Cnt + 1.f);
        out[0] = 0.5f * phat * (1.f + erff(phat * 0.70710678118654752f));
    }
}

extern "C" void kernel_launch(void* const* d_in, const int* in_sizes, int n_in,
                              void* d_out, int out_size, void* d_ws, size_t ws_size,
                              hipStream_t stream) {
    const float* z0   = (const float*)d_in[0];
    const float* z1   = (const float*)d_in[1];
    const float* Wemb = (const float*)d_in[2];
    const float* bemb = (const float*)d_in[3];
    const float* W1   = (const float*)d_in[4];
    const float* b1   = (const float*)d_in[5];
    const float* bn1g = (const float*)d_in[6];
    const float* bn1b = (const float*)d_in[7];
    const float* bn1m = (const float*)d_in[8];
    const float* bn1v = (const float*)d_in[9];
    const float* W2   = (const float*)d_in[10];
    const float* b2   = (const float*)d_in[11];
    const float* bn2g = (const float*)d_in[12];
    const float* bn2b = (const float*)d_in[13];
    const float* bn2m = (const float*)d_in[14];
    const float* bn2v = (const float*)d_in[15];
    const float* gam  = (const float*)d_in[16];

    float* ws   = (float*)d_ws;
    float* e0   = ws;                                    // 80,000 f32
    float* e1   = ws + 80000;                            // 80,000 f32
    __hip_bfloat16* Bmap = (__hip_bfloat16*)(ws + 160000);  // 50*PLANE bf16
    float* Cpart = ws + 160000 + 16483200;               // 10 x 640,000 f32
    float* Cbuf  = Cpart + 6400000;                      // 640,000 f32
    float* yhat  = Cbuf + 640000;                        // 7,921 f32
    unsigned short* Bh = (unsigned short*)(yhat + 8000); // 14,336 u16
    float* out  = (float*)d_out;

    kembed<<<200, 256, 0, stream>>>(z0, z1, Wemb, bemb, e0, e1);
    kprepW<<<56, 256, 0, stream>>>(W1, Bh);
    kzero<<<(50 * 17696 + 255) / 256, 256, 0, stream>>>((unsigned short*)Bmap);
    dim3 gi(100, 13);
    kinter<<<gi, 256, 0, stream>>>(e0, e1, Bh, b1, bn1g, bn1b, bn1m, bn1v, Bmap);
    dim3 gc(13, 13, 10);
    kconv<<<gc, 256, 0, stream>>>(Bmap, W2, Cpart);
    kreduce<<<(160000 + 255) / 256, 256, 0, stream>>>(Cpart, b2, bn2g, bn2b, bn2m, bn2v, Cbuf);
    kpool<<<(89 * 89 + 255) / 256, 256, 0, stream>>>(Cbuf, yhat);
    kfinal<<<1, 256, 0, stream>>>(yhat, gam, out);
}

// Round 8
// 208.552 us; speedup vs baseline: 1.3456x; 1.3456x over previous
//
#include <hip/hip_runtime.h>
#include <hip/hip_bf16.h>
#include <math.h>

#define EPS 1e-5f
#define ST 816                 // padded Bmap row stride (elems)
#define PLANE (816 * 808)      // padded plane elems

typedef _Float16 f16x8 __attribute__((ext_vector_type(8)));
typedef float f32x4 __attribute__((ext_vector_type(4)));

__device__ __forceinline__ float elu_f(float x) {
    return x > 0.f ? x : __expf(x) - 1.f;
}

// ---------------- Kernel 1: e = elu(z @ W_emb^T + b_emb) ----------------
__global__ __launch_bounds__(256) void kembed(const float* __restrict__ z0,
                                              const float* __restrict__ z1,
                                              const float* __restrict__ Wemb,
                                              const float* __restrict__ bemb,
                                              float* __restrict__ e0,
                                              float* __restrict__ e1) {
    __shared__ float4 zs4[2048];  // 8 rows x 1024 floats
    int src = blockIdx.x & 1;
    int rowbase = (blockIdx.x >> 1) * 8;
    const float* z = src ? z1 : z0;
    float* e = src ? e1 : e0;
    const float4* zrow4 = reinterpret_cast<const float4*>(z + rowbase * 1024);
    for (int idx = threadIdx.x; idx < 2048; idx += 256) zs4[idx] = zrow4[idx];
    __syncthreads();
    int t = threadIdx.x;
    if (t < 200) {
        int d = t % 100;
        int half = t / 100;
        const float4* w4 = reinterpret_cast<const float4*>(Wemb + d * 1024);
        float acc[4] = {0.f, 0.f, 0.f, 0.f};
        for (int k = 0; k < 256; k++) {
            float4 w = w4[k];
#pragma unroll
            for (int r = 0; r < 4; r++) {
                float4 zv = zs4[(half * 4 + r) * 256 + k];
                acc[r] = fmaf(w.x, zv.x, acc[r]);
                acc[r] = fmaf(w.y, zv.y, acc[r]);
                acc[r] = fmaf(w.z, zv.z, acc[r]);
                acc[r] = fmaf(w.w, zv.w, acc[r]);
            }
        }
        float be = bemb[d];
#pragma unroll
        for (int r = 0; r < 4; r++) {
            e[(rowbase + half * 4 + r) * 100 + d] = elu_f(acc[r] + be);
        }
    }
}

// ---------------- Prep: pack W1 as fp16 B-fragments, d-interleaved K ----------------
__global__ __launch_bounds__(256) void kprepW(const float* __restrict__ W1,
                                              unsigned short* __restrict__ Bh) {
    int idx = blockIdx.x * 256 + threadIdx.x;
    if (idx >= 14336) return;
    int i = idx & 7;
    int lane = (idx >> 3) & 63;
    int hf = (idx >> 9) & 3;
    int ks = idx >> 11;              // 0..6
    int h = hf * 16 + (lane & 15);
    int k = ks * 32 + (lane >> 4) * 8 + i;
    int d = k >> 1;
    int term = k & 1;
    float val = (d < 100 && h < 50) ? W1[h * 200 + term * 100 + d] : 0.f;
    _Float16 hv = (_Float16)val;
    Bh[idx] = __builtin_bit_cast(unsigned short, hv);
}

// ---------------- kzero: zero the halo borders of padded Bmap ----------------
__global__ __launch_bounds__(256) void kzero(unsigned short* __restrict__ Bmap) {
    const int per = 4896 + 12800;
    int idx = blockIdx.x * 256 + threadIdx.x;
    if (idx >= 50 * per) return;
    int h = idx / per, q = idx % per;
    int row, col;
    if (q < 4896) {
        int rr = q / 816;
        col = q - rr * 816;
        row = rr < 3 ? rr : 800 + rr;
    } else {
        int q2 = q - 4896;
        row = 3 + (q2 >> 4);
        int m = q2 & 15;
        col = m < 8 ? m : 800 + m;
    }
    Bmap[(size_t)h * PLANE + (size_t)row * ST + col] = 0;
}

// ---------------- Kernel 2: interaction GEMM via MFMA (fp16) ----------------
// grid (100,25), block 256 = 4 waves. Tile 8 i x 32 j. Wave owns 2 i (fl), 2 j-frags.
__global__ __launch_bounds__(256) void kinter(const float* __restrict__ e0,
                                              const float* __restrict__ e1,
                                              const unsigned short* __restrict__ Bh,
                                              const float* __restrict__ b1,
                                              const float* __restrict__ g1,
                                              const float* __restrict__ bb1,
                                              const float* __restrict__ m1,
                                              const float* __restrict__ v1,
                                              __hip_bfloat16* __restrict__ Bmap) {
    __shared__ float e0s[8][116];
    __shared__ float e1s[32][116];
    int i0 = blockIdx.x * 8, j0 = blockIdx.y * 32;
    int tid = threadIdx.x;
    for (int idx = tid; idx < 40 * 116; idx += 256) {
        int r = idx / 116, c = idx % 116;
        float v = 0.f;
        if (c < 100) {
            v = (r < 8) ? e0[(i0 + r) * 100 + c] : e1[(j0 + r - 8) * 100 + c];
        }
        if (r < 8) e0s[r][c] = v;
        else e1s[r - 8][c] = v;
    }
    __syncthreads();

    int lane = tid & 63;
    int wid = tid >> 6;
    int g = lane >> 4;        // k-subchunk 0..3
    int jrow = lane & 15;     // A-row = j within frag

    f32x4 acc[2][2][4] = {};  // [fl][jf][hf]

    for (int ks = 0; ks < 7; ++ks) {
        f16x8 b[4];
#pragma unroll
        for (int hf = 0; hf < 4; ++hf) {
            int fidx = ((ks * 4 + hf) * 64 + lane) * 8;
            b[hf] = __builtin_bit_cast(f16x8, *(const uint4*)(Bh + fidx));
        }
        int d0 = ks * 16 + g * 4;
        float4 x0v[2];
        x0v[0] = *(const float4*)&e0s[wid * 2 + 0][d0];
        x0v[1] = *(const float4*)&e0s[wid * 2 + 1][d0];
#pragma unroll
        for (int jf = 0; jf < 2; ++jf) {
            float4 x1 = *(const float4*)&e1s[jf * 16 + jrow][d0];
#pragma unroll
            for (int fl = 0; fl < 2; ++fl) {
                float4 x0 = x0v[fl];
                unsigned int u0 = __builtin_bit_cast(unsigned int,
                    __builtin_amdgcn_cvt_pkrtz(fabsf(x0.x - x1.x), x0.x * x1.x));
                unsigned int u1 = __builtin_bit_cast(unsigned int,
                    __builtin_amdgcn_cvt_pkrtz(fabsf(x0.y - x1.y), x0.y * x1.y));
                unsigned int u2 = __builtin_bit_cast(unsigned int,
                    __builtin_amdgcn_cvt_pkrtz(fabsf(x0.z - x1.z), x0.z * x1.z));
                unsigned int u3 = __builtin_bit_cast(unsigned int,
                    __builtin_amdgcn_cvt_pkrtz(fabsf(x0.w - x1.w), x0.w * x1.w));
                uint4 au = {u0, u1, u2, u3};
                f16x8 a = __builtin_bit_cast(f16x8, au);
#pragma unroll
                for (int hf = 0; hf < 4; ++hf) {
                    acc[fl][jf][hf] = __builtin_amdgcn_mfma_f32_16x16x32_f16(
                        a, b[hf], acc[fl][jf][hf], 0, 0, 0);
                }
            }
        }
    }

    // epilogue: D[row=j][col=h]; lane (g,hl): rows j = jf*16 + g*4 + r, col h = hf*16+hl
    int hl = lane & 15;
#pragma unroll
    for (int hf = 0; hf < 4; ++hf) {
        int h = hf * 16 + hl;
        bool ok = h < 50;
        int hc = ok ? h : 0;
        float bnb = b1[hc];
        float sc = g1[hc] * rsqrtf(v1[hc] + EPS);
        float off = bb1[hc] - m1[hc] * sc;
#pragma unroll
        for (int fl = 0; fl < 2; ++fl) {
            int i = i0 + wid * 2 + fl;
#pragma unroll
            for (int jf = 0; jf < 2; ++jf) {
                int j = j0 + jf * 16 + g * 4;
                f32x4 a = acc[fl][jf][hf];
                unsigned short o[4];
#pragma unroll
                for (int r = 0; r < 4; ++r) {
                    float x = a[r] + bnb;
                    x = elu_f(x);
                    x = fmaf(x, sc, off);
                    x = elu_f(x);
                    o[r] = __builtin_bit_cast(unsigned short, (__bf16)x);
                }
                if (ok) {
                    *(ushort4*)&Bmap[(size_t)h * PLANE + (size_t)(i + 3) * ST + (j + 8)] =
                        *(ushort4*)o;
                }
            }
        }
    }
}

// ---------------- Kernel 3: 7x7 conv, 64x64 tile, async reg-staged channels ----------------
// grid (13,13,10). tile[70][84]; b128 LDS reads (bank floor); scalar W2 loads;
// next channel prefetched into 3 uint4 regs while current channel computes.
__device__ __forceinline__ void unpack8(float* tile_row, uint4 v) {
    float f[8];
    f[0] = __uint_as_float(v.x << 16);
    f[1] = __uint_as_float(v.x & 0xFFFF0000u);
    f[2] = __uint_as_float(v.y << 16);
    f[3] = __uint_as_float(v.y & 0xFFFF0000u);
    f[4] = __uint_as_float(v.z << 16);
    f[5] = __uint_as_float(v.z & 0xFFFF0000u);
    f[6] = __uint_as_float(v.w << 16);
    f[7] = __uint_as_float(v.w & 0xFFFF0000u);
    *(float4*)&tile_row[0] = *(float4*)&f[0];
    *(float4*)&tile_row[4] = *(float4*)&f[4];
}

__global__ __launch_bounds__(256) void kconv(const __hip_bfloat16* __restrict__ Bmap,
                                             const float* __restrict__ W2,
                                             float* __restrict__ Cpart) {
    __shared__ float tile[70][84];
    int bx = blockIdx.x, by = blockIdx.y, zc = blockIdx.z;
    int h0 = zc * 5;
    int tid = threadIdx.x;
    int lx = tid & 15, ly = tid >> 4;     // 16 x 16 threads, 4x4 outputs each

    // staging slots: u = tid, tid+256, tid+512 (u < 700)
    int u0 = tid, u1 = tid + 256, u2 = tid + 512;
    int r0 = u0 / 10, k0 = u0 - r0 * 10;
    int r1 = u1 / 10, k1 = u1 - r1 * 10;
    int r2 = u2 / 10, k2 = u2 - r2 * 10;
    bool has2 = (u2 < 700);
    const __hip_bfloat16* base = Bmap + (size_t)h0 * PLANE;
    size_t o0 = (size_t)(64 * by + r0) * ST + 64 * bx + 8 * k0;
    size_t o1 = (size_t)(64 * by + r1) * ST + 64 * bx + 8 * k1;
    size_t o2 = (size_t)(64 * by + r2) * ST + 64 * bx + 8 * k2;

    uint4 s0 = *(const uint4*)(base + o0);
    uint4 s1 = *(const uint4*)(base + o1);
    uint4 s2 = has2 ? *(const uint4*)(base + o2) : uint4{0, 0, 0, 0};

    float acc[4][4] = {};
    for (int hh = 0; hh < 5; ++hh) {
        __syncthreads();                    // previous compute done; LDS reusable
        unpack8(&tile[r0][8 * k0], s0);
        unpack8(&tile[r1][8 * k1], s1);
        if (has2) unpack8(&tile[r2][8 * k2], s2);
        if (hh < 4) {                       // issue next channel's loads now;
            const __hip_bfloat16* nb = base + (size_t)(hh + 1) * PLANE;
            s0 = *(const uint4*)(nb + o0);  // latency hides under compute below
            s1 = *(const uint4*)(nb + o1);
            if (has2) s2 = *(const uint4*)(nb + o2);
        }
        __syncthreads();                    // tile ready
        const float* wp = W2 + (h0 + hh) * 49;   // block-uniform -> scalar loads
#pragma unroll
        for (int r = 0; r < 10; ++r) {
            float w[12];
            *(float4*)&w[0] = *(const float4*)&tile[4 * ly + r][4 * lx + 4];
            *(float4*)&w[4] = *(const float4*)&tile[4 * ly + r][4 * lx + 8];
            *(float4*)&w[8] = *(const float4*)&tile[4 * ly + r][4 * lx + 12];
#pragma unroll
            for (int rr = 0; rr < 4; ++rr) {
                int di = r - rr;
                if (di < 0 || di > 6) continue;
#pragma unroll
                for (int dj = 0; dj < 7; ++dj) {
                    float wt = wp[di * 7 + dj];
#pragma unroll
                    for (int cc = 0; cc < 4; ++cc)
                        acc[rr][cc] = fmaf(w[cc + dj + 1], wt, acc[rr][cc]);
                }
            }
        }
    }
    int j = 64 * bx + 4 * lx;
    if (j < 800) {
#pragma unroll
        for (int rr = 0; rr < 4; ++rr) {
            int i = 64 * by + 4 * ly + rr;
            if (i < 800)
                *(float4*)&Cpart[(size_t)zc * 640000 + (size_t)i * 800 + j] =
                    *(float4*)acc[rr];
        }
    }
}

// ---------------- Kernel 3b: reduce partials + bias + bn2 ----------------
__global__ __launch_bounds__(256) void kreduce(const float* __restrict__ Cpart,
                                               const float* __restrict__ b2,
                                               const float* __restrict__ g2,
                                               const float* __restrict__ bb2,
                                               const float* __restrict__ m2,
                                               const float* __restrict__ v2,
                                               float* __restrict__ C) {
    int idx = blockIdx.x * 256 + threadIdx.x;
    if (idx >= 160000) return;
    float s2 = g2[0] * rsqrtf(v2[0] + EPS);
    float t2 = bb2[0] - m2[0] * s2;
    float bias = b2[0];
    float4 s = ((const float4*)Cpart)[idx];
#pragma unroll
    for (int z = 1; z < 10; z++) {
        float4 p = ((const float4*)(Cpart + (size_t)z * 640000))[idx];
        s.x += p.x; s.y += p.y; s.z += p.z; s.w += p.w;
    }
    s.x = (s.x + bias) * s2 + t2;
    s.y = (s.y + bias) * s2 + t2;
    s.z = (s.z + bias) * s2 + t2;
    s.w = (s.w + bias) * s2 + t2;
    ((float4*)C)[idx] = s;
}

// ---------------- Kernel 4: 9x9/9 maxpool with pad 4 -> yhat (89x89) ----------------
__global__ __launch_bounds__(256) void kpool(const float* __restrict__ C,
                                             float* __restrict__ yhat) {
    int idx = blockIdx.x * 256 + threadIdx.x;
    if (idx >= 89 * 89) return;
    int oy = idx / 89, ox = idx % 89;
    float mx = -INFINITY;
    int y0 = oy * 9 - 4, x0 = ox * 9 - 4;
    for (int dy = 0; dy < 9; dy++) {
        int y = y0 + dy;
        if (y < 0 || y >= 800) continue;
        for (int dx = 0; dx < 9; dx++) {
            int x = x0 + dx;
            if (x < 0 || x >= 800) continue;
            mx = fmaxf(mx, C[y * 800 + x]);
        }
    }
    yhat[idx] = mx;
}

// ---------------- Kernel 5: mean/var -> Q -> phat -> gelu ----------------
__global__ __launch_bounds__(256) void kfinal(const float* __restrict__ yhat,
                                              const float* __restrict__ gamma,
                                              float* __restrict__ out) {
    const int N = 89 * 89;
    __shared__ float sA[4], sB[4];
    int tid = threadIdx.x;
    int wid = tid >> 6, lane = tid & 63;
    float s = 0.f, ss = 0.f;
    for (int i = tid; i < N; i += 256) {
        float y = yhat[i];
        s += y;
        ss = fmaf(y, y, ss);
    }
    for (int off = 32; off; off >>= 1) {
        s += __shfl_down(s, off);
        ss += __shfl_down(ss, off);
    }
    if (lane == 0) { sA[wid] = s; sB[wid] = ss; }
    __syncthreads();
    float S = sA[0] + sA[1] + sA[2] + sA[3];
    float SS = sB[0] + sB[1] + sB[2] + sB[3];
    float mu = S / (float)N;
    float var = (SS - S * S / (float)N) / (float)(N - 1);
    float thr = mu + gamma[0] * var;
    __syncthreads();
    float q = 0.f, c = 0.f;
    for (int i = tid; i < N; i += 256) {
        float d = yhat[i] - thr;
        if (d > 0.f) { q += d; c += 1.f; }
    }
    for (int off = 32; off; off >>= 1) {
        q += __shfl_down(q, off);
        c += __shfl_down(c, off);
    }
    if (lane == 0) { sA[wid] = q; sB[wid] = c; }
    __syncthreads();
    if (tid == 0) {
        float Q = sA[0] + sA[1] + sA[2] + sA[3];
        float Cnt = sB[0] + sB[1] + sB[2] + sB[3];
        float phat = Q / (Cnt + 1.f);
        out[0] = 0.5f * phat * (1.f + erff(phat * 0.70710678118654752f));
    }
}

extern "C" void kernel_launch(void* const* d_in, const int* in_sizes, int n_in,
                              void* d_out, int out_size, void* d_ws, size_t ws_size,
                              hipStream_t stream) {
    const float* z0   = (const float*)d_in[0];
    const float* z1   = (const float*)d_in[1];
    const float* Wemb = (const float*)d_in[2];
    const float* bemb = (const float*)d_in[3];
    const float* W1   = (const float*)d_in[4];
    const float* b1   = (const float*)d_in[5];
    const float* bn1g = (const float*)d_in[6];
    const float* bn1b = (const float*)d_in[7];
    const float* bn1m = (const float*)d_in[8];
    const float* bn1v = (const float*)d_in[9];
    const float* W2   = (const float*)d_in[10];
    const float* b2   = (const float*)d_in[11];
    const float* bn2g = (const float*)d_in[12];
    const float* bn2b = (const float*)d_in[13];
    const float* bn2m = (const float*)d_in[14];
    const float* bn2v = (const float*)d_in[15];
    const float* gam  = (const float*)d_in[16];

    float* ws   = (float*)d_ws;
    float* e0   = ws;                                    // 80,000 f32
    float* e1   = ws + 80000;                            // 80,000 f32
    __hip_bfloat16* Bmap = (__hip_bfloat16*)(ws + 160000);  // 50*PLANE bf16
    float* Cpart = ws + 160000 + 16483200;               // 10 x 640,000 f32
    float* Cbuf  = Cpart + 6400000;                      // 640,000 f32
    float* yhat  = Cbuf + 640000;                        // 7,921 f32
    unsigned short* Bh = (unsigned short*)(yhat + 8000); // 14,336 u16
    float* out  = (float*)d_out;

    kembed<<<200, 256, 0, stream>>>(z0, z1, Wemb, bemb, e0, e1);
    kprepW<<<56, 256, 0, stream>>>(W1, Bh);
    kzero<<<(50 * 17696 + 255) / 256, 256, 0, stream>>>((unsigned short*)Bmap);
    dim3 gi(100, 25);
    kinter<<<gi, 256, 0, stream>>>(e0, e1, Bh, b1, bn1g, bn1b, bn1m, bn1v, Bmap);
    dim3 gc(13, 13, 10);
    kconv<<<gc, 256, 0, stream>>>(Bmap, W2, Cpart);
    kreduce<<<(160000 + 255) / 256, 256, 0, stream>>>(Cpart, b2, bn2g, bn2b, bn2m, bn2v, Cbuf);
    kpool<<<(89 * 89 + 255) / 256, 256, 0, stream>>>(Cbuf, yhat);
    kfinal<<<1, 256, 0, stream>>>(yhat, gam, out);
}

// Round 9
// 208.207 us; speedup vs baseline: 1.3478x; 1.0017x over previous
//
#include <hip/hip_runtime.h>
#include <hip/hip_bf16.h>
#include <math.h>

#define EPS 1e-5f
#define ST 816                 // padded Bmap row stride (elems)
#define PLANE (816 * 808)      // padded plane elems

typedef _Float16 f16x8 __attribute__((ext_vector_type(8)));
typedef float f32x4 __attribute__((ext_vector_type(4)));

__device__ __forceinline__ float elu_f(float x) {
    return x > 0.f ? x : __expf(x) - 1.f;
}

// ---------------- Merged prep: kembed (blocks 0..199) + kprepW (200..255) + kzero (256..687) ----------------
__global__ __launch_bounds__(256) void kprep(const float* __restrict__ z0,
                                             const float* __restrict__ z1,
                                             const float* __restrict__ Wemb,
                                             const float* __restrict__ bemb,
                                             float* __restrict__ e0,
                                             float* __restrict__ e1,
                                             const float* __restrict__ W1,
                                             unsigned short* __restrict__ Bh,
                                             unsigned short* __restrict__ Bmap) {
    __shared__ float4 zs4[2048];  // 8 rows x 1024 floats (kembed only)
    int b = blockIdx.x;
    int tid = threadIdx.x;
    if (b < 200) {
        // ---- kembed ----
        int src = b & 1;
        int rowbase = (b >> 1) * 8;
        const float* z = src ? z1 : z0;
        float* e = src ? e1 : e0;
        const float4* zrow4 = reinterpret_cast<const float4*>(z + rowbase * 1024);
        for (int idx = tid; idx < 2048; idx += 256) zs4[idx] = zrow4[idx];
        __syncthreads();
        if (tid < 200) {
            int d = tid % 100;
            int half = tid / 100;
            const float4* w4 = reinterpret_cast<const float4*>(Wemb + d * 1024);
            float acc[4] = {0.f, 0.f, 0.f, 0.f};
            for (int k = 0; k < 256; k++) {
                float4 w = w4[k];
#pragma unroll
                for (int r = 0; r < 4; r++) {
                    float4 zv = zs4[(half * 4 + r) * 256 + k];
                    acc[r] = fmaf(w.x, zv.x, acc[r]);
                    acc[r] = fmaf(w.y, zv.y, acc[r]);
                    acc[r] = fmaf(w.z, zv.z, acc[r]);
                    acc[r] = fmaf(w.w, zv.w, acc[r]);
                }
            }
            float be = bemb[d];
#pragma unroll
            for (int r = 0; r < 4; r++) {
                e[(rowbase + half * 4 + r) * 100 + d] = elu_f(acc[r] + be);
            }
        }
    } else if (b < 256) {
        // ---- kprepW: pack W1 as fp16 B-fragments, d-interleaved K (k = 2d+term, K=224) ----
        int idx = (b - 200) * 256 + tid;   // 0..14335 exactly
        int i = idx & 7;
        int lane = (idx >> 3) & 63;
        int hf = (idx >> 9) & 3;
        int ks = idx >> 11;                // 0..6
        int h = hf * 16 + (lane & 15);
        int k = ks * 32 + (lane >> 4) * 8 + i;
        int d = k >> 1;
        int term = k & 1;
        float val = (d < 100 && h < 50) ? W1[h * 200 + term * 100 + d] : 0.f;
        _Float16 hv = (_Float16)val;
        Bh[idx] = __builtin_bit_cast(unsigned short, hv);
    } else {
        // ---- kzero (vectorized): zero halo borders of padded Bmap ----
        // per plane: 6 full rows (102 uint4 each) + 800 rows x 2 side uint4s = 2212 uint4
        int idx = (b - 256) * 256 + tid;
        if (idx < 110600) {
            int h = idx / 2212, q = idx % 2212;
            int row, colv;
            if (q < 612) {
                int rr = q / 102;
                colv = q - rr * 102;
                row = rr < 3 ? rr : 800 + rr;
            } else {
                int q2 = q - 612;
                row = 3 + (q2 >> 1);
                colv = (q2 & 1) ? 101 : 0;
            }
            uint4 zz = {0, 0, 0, 0};
            *(uint4*)&Bmap[(size_t)h * PLANE + (size_t)row * ST + colv * 8] = zz;
        }
    }
}

// ---------------- Kernel 2: interaction GEMM via MFMA (fp16) ----------------
// grid (100,25), block 256 = 4 waves. Tile 8 i x 32 j. Wave owns 2 i (fl), 2 j-frags.
__global__ __launch_bounds__(256) void kinter(const float* __restrict__ e0,
                                              const float* __restrict__ e1,
                                              const unsigned short* __restrict__ Bh,
                                              const float* __restrict__ b1,
                                              const float* __restrict__ g1,
                                              const float* __restrict__ bb1,
                                              const float* __restrict__ m1,
                                              const float* __restrict__ v1,
                                              __hip_bfloat16* __restrict__ Bmap) {
    __shared__ float e0s[8][116];
    __shared__ float e1s[32][116];
    int i0 = blockIdx.x * 8, j0 = blockIdx.y * 32;
    int tid = threadIdx.x;
    for (int idx = tid; idx < 40 * 116; idx += 256) {
        int r = idx / 116, c = idx % 116;
        float v = 0.f;
        if (c < 100) {
            v = (r < 8) ? e0[(i0 + r) * 100 + c] : e1[(j0 + r - 8) * 100 + c];
        }
        if (r < 8) e0s[r][c] = v;
        else e1s[r - 8][c] = v;
    }
    __syncthreads();

    int lane = tid & 63;
    int wid = tid >> 6;
    int g = lane >> 4;        // k-subchunk 0..3
    int jrow = lane & 15;     // A-row = j within frag

    f32x4 acc[2][2][4] = {};  // [fl][jf][hf]

    for (int ks = 0; ks < 7; ++ks) {
        f16x8 b[4];
#pragma unroll
        for (int hf = 0; hf < 4; ++hf) {
            int fidx = ((ks * 4 + hf) * 64 + lane) * 8;
            b[hf] = __builtin_bit_cast(f16x8, *(const uint4*)(Bh + fidx));
        }
        int d0 = ks * 16 + g * 4;
        float4 x0v[2];
        x0v[0] = *(const float4*)&e0s[wid * 2 + 0][d0];
        x0v[1] = *(const float4*)&e0s[wid * 2 + 1][d0];
#pragma unroll
        for (int jf = 0; jf < 2; ++jf) {
            float4 x1 = *(const float4*)&e1s[jf * 16 + jrow][d0];
#pragma unroll
            for (int fl = 0; fl < 2; ++fl) {
                float4 x0 = x0v[fl];
                unsigned int u0 = __builtin_bit_cast(unsigned int,
                    __builtin_amdgcn_cvt_pkrtz(fabsf(x0.x - x1.x), x0.x * x1.x));
                unsigned int u1 = __builtin_bit_cast(unsigned int,
                    __builtin_amdgcn_cvt_pkrtz(fabsf(x0.y - x1.y), x0.y * x1.y));
                unsigned int u2 = __builtin_bit_cast(unsigned int,
                    __builtin_amdgcn_cvt_pkrtz(fabsf(x0.z - x1.z), x0.z * x1.z));
                unsigned int u3 = __builtin_bit_cast(unsigned int,
                    __builtin_amdgcn_cvt_pkrtz(fabsf(x0.w - x1.w), x0.w * x1.w));
                uint4 au = {u0, u1, u2, u3};
                f16x8 a = __builtin_bit_cast(f16x8, au);
#pragma unroll
                for (int hf = 0; hf < 4; ++hf) {
                    acc[fl][jf][hf] = __builtin_amdgcn_mfma_f32_16x16x32_f16(
                        a, b[hf], acc[fl][jf][hf], 0, 0, 0);
                }
            }
        }
    }

    // epilogue: D[row=j][col=h]; lane (g,hl): rows j = jf*16 + g*4 + r, col h = hf*16+hl
    int hl = lane & 15;
#pragma unroll
    for (int hf = 0; hf < 4; ++hf) {
        int h = hf * 16 + hl;
        bool ok = h < 50;
        int hc = ok ? h : 0;
        float bnb = b1[hc];
        float sc = g1[hc] * rsqrtf(v1[hc] + EPS);
        float off = bb1[hc] - m1[hc] * sc;
#pragma unroll
        for (int fl = 0; fl < 2; ++fl) {
            int i = i0 + wid * 2 + fl;
#pragma unroll
            for (int jf = 0; jf < 2; ++jf) {
                int j = j0 + jf * 16 + g * 4;
                f32x4 a = acc[fl][jf][hf];
                unsigned short o[4];
#pragma unroll
                for (int r = 0; r < 4; ++r) {
                    float x = a[r] + bnb;
                    x = elu_f(x);
                    x = fmaf(x, sc, off);
                    x = elu_f(x);
                    o[r] = __builtin_bit_cast(unsigned short, (__bf16)x);
                }
                if (ok) {
                    *(ushort4*)&Bmap[(size_t)h * PLANE + (size_t)(i + 3) * ST + (j + 8)] =
                        *(ushort4*)o;
                }
            }
        }
    }
}

// ---------------- Kernel 3: 7x7 conv, 64x64 tile, double-buffered LDS (1 barrier/ch) ----------------
__device__ __forceinline__ void unpack8(float* tile_row, uint4 v) {
    float f[8];
    f[0] = __uint_as_float(v.x << 16);
    f[1] = __uint_as_float(v.x & 0xFFFF0000u);
    f[2] = __uint_as_float(v.y << 16);
    f[3] = __uint_as_float(v.y & 0xFFFF0000u);
    f[4] = __uint_as_float(v.z << 16);
    f[5] = __uint_as_float(v.z & 0xFFFF0000u);
    f[6] = __uint_as_float(v.w << 16);
    f[7] = __uint_as_float(v.w & 0xFFFF0000u);
    *(float4*)&tile_row[0] = *(float4*)&f[0];
    *(float4*)&tile_row[4] = *(float4*)&f[4];
}

__global__ __launch_bounds__(256) void kconv(const __hip_bfloat16* __restrict__ Bmap,
                                             const float* __restrict__ W2,
                                             float* __restrict__ Cpart) {
    __shared__ float tile[2][70][84];
    int bx = blockIdx.x, by = blockIdx.y, zc = blockIdx.z;
    int h0 = zc * 5;
    int tid = threadIdx.x;
    int lx = tid & 15, ly = tid >> 4;     // 16 x 16 threads, 4x4 outputs each

    int u0 = tid, u1 = tid + 256, u2 = tid + 512;
    int r0 = u0 / 10, k0 = u0 - r0 * 10;
    int r1 = u1 / 10, k1 = u1 - r1 * 10;
    int r2 = u2 / 10, k2 = u2 - r2 * 10;
    bool has2 = (u2 < 700);
    const __hip_bfloat16* base = Bmap + (size_t)h0 * PLANE;
    size_t o0 = (size_t)(64 * by + r0) * ST + 64 * bx + 8 * k0;
    size_t o1 = (size_t)(64 * by + r1) * ST + 64 * bx + 8 * k1;
    size_t o2 = (size_t)(64 * by + r2) * ST + 64 * bx + 8 * k2;

    // ch0 -> buf0 (no barrier needed yet; first use is after the hh=0 barrier)
    {
        uint4 t0 = *(const uint4*)(base + o0);
        uint4 t1 = *(const uint4*)(base + o1);
        uint4 t2 = has2 ? *(const uint4*)(base + o2) : uint4{0, 0, 0, 0};
        unpack8(&tile[0][r0][8 * k0], t0);
        unpack8(&tile[0][r1][8 * k1], t1);
        if (has2) unpack8(&tile[0][r2][8 * k2], t2);
    }
    // preload ch1 into regs
    uint4 s0 = *(const uint4*)(base + PLANE + o0);
    uint4 s1 = *(const uint4*)(base + PLANE + o1);
    uint4 s2 = has2 ? *(const uint4*)(base + PLANE + o2) : uint4{0, 0, 0, 0};

    float acc[4][4] = {};
    for (int hh = 0; hh < 5; ++hh) {
        int cur = hh & 1;
        __syncthreads();   // buf[cur] fully written; buf[cur^1] fully consumed
        if (hh < 4) {
            unpack8(&tile[cur ^ 1][r0][8 * k0], s0);   // write ch hh+1
            unpack8(&tile[cur ^ 1][r1][8 * k1], s1);
            if (has2) unpack8(&tile[cur ^ 1][r2][8 * k2], s2);
            if (hh < 3) {                              // issue loads for ch hh+2
                const __hip_bfloat16* nb = base + (size_t)(hh + 2) * PLANE;
                s0 = *(const uint4*)(nb + o0);
                s1 = *(const uint4*)(nb + o1);
                if (has2) s2 = *(const uint4*)(nb + o2);
            }
        }
        const float* wp = W2 + (h0 + hh) * 49;   // block-uniform -> scalar loads
#pragma unroll
        for (int r = 0; r < 10; ++r) {
            float w[12];
            *(float4*)&w[0] = *(const float4*)&tile[cur][4 * ly + r][4 * lx + 4];
            *(float4*)&w[4] = *(const float4*)&tile[cur][4 * ly + r][4 * lx + 8];
            *(float4*)&w[8] = *(const float4*)&tile[cur][4 * ly + r][4 * lx + 12];
#pragma unroll
            for (int rr = 0; rr < 4; ++rr) {
                int di = r - rr;
                if (di < 0 || di > 6) continue;
#pragma unroll
                for (int dj = 0; dj < 7; ++dj) {
                    float wt = wp[di * 7 + dj];
#pragma unroll
                    for (int cc = 0; cc < 4; ++cc)
                        acc[rr][cc] = fmaf(w[cc + dj + 1], wt, acc[rr][cc]);
                }
            }
        }
    }
    int j = 64 * bx + 4 * lx;
    if (j < 800) {
#pragma unroll
        for (int rr = 0; rr < 4; ++rr) {
            int i = 64 * by + 4 * ly + rr;
            if (i < 800)
                *(float4*)&Cpart[(size_t)zc * 640000 + (size_t)i * 800 + j] =
                    *(float4*)acc[rr];
        }
    }
}

// ---------------- Kernel 3b: reduce partials + bias + bn2 ----------------
__global__ __launch_bounds__(256) void kreduce(const float* __restrict__ Cpart,
                                               const float* __restrict__ b2,
                                               const float* __restrict__ g2,
                                               const float* __restrict__ bb2,
                                               const float* __restrict__ m2,
                                               const float* __restrict__ v2,
                                               float* __restrict__ C) {
    int idx = blockIdx.x * 256 + threadIdx.x;
    if (idx >= 160000) return;
    float s2 = g2[0] * rsqrtf(v2[0] + EPS);
    float t2 = bb2[0] - m2[0] * s2;
    float bias = b2[0];
    float4 s = ((const float4*)Cpart)[idx];
#pragma unroll
    for (int z = 1; z < 10; z++) {
        float4 p = ((const float4*)(Cpart + (size_t)z * 640000))[idx];
        s.x += p.x; s.y += p.y; s.z += p.z; s.w += p.w;
    }
    s.x = (s.x + bias) * s2 + t2;
    s.y = (s.y + bias) * s2 + t2;
    s.z = (s.z + bias) * s2 + t2;
    s.w = (s.w + bias) * s2 + t2;
    ((float4*)C)[idx] = s;
}

// ---------------- Kernel 4: 9x9/9 maxpool with pad 4 -> yhat (89x89) ----------------
__global__ __launch_bounds__(256) void kpool(const float* __restrict__ C,
                                             float* __restrict__ yhat) {
    int idx = blockIdx.x * 256 + threadIdx.x;
    if (idx >= 89 * 89) return;
    int oy = idx / 89, ox = idx % 89;
    float mx = -INFINITY;
    int y0 = oy * 9 - 4, x0 = ox * 9 - 4;
    for (int dy = 0; dy < 9; dy++) {
        int y = y0 + dy;
        if (y < 0 || y >= 800) continue;
        for (int dx = 0; dx < 9; dx++) {
            int x = x0 + dx;
            if (x < 0 || x >= 800) continue;
            mx = fmaxf(mx, C[y * 800 + x]);
        }
    }
    yhat[idx] = mx;
}

// ---------------- Kernel 5: mean/var -> Q -> phat -> gelu ----------------
__global__ __launch_bounds__(256) void kfinal(const float* __restrict__ yhat,
                                              const float* __restrict__ gamma,
                                              float* __restrict__ out) {
    const int N = 89 * 89;
    __shared__ float sA[4], sB[4];
    int tid = threadIdx.x;
    int wid = tid >> 6, lane = tid & 63;
    float s = 0.f, ss = 0.f;
    for (int i = tid; i < N; i += 256) {
        float y = yhat[i];
        s += y;
        ss = fmaf(y, y, ss);
    }
    for (int off = 32; off; off >>= 1) {
        s += __shfl_down(s, off);
        ss += __shfl_down(ss, off);
    }
    if (lane == 0) { sA[wid] = s; sB[wid] = ss; }
    __syncthreads();
    float S = sA[0] + sA[1] + sA[2] + sA[3];
    float SS = sB[0] + sB[1] + sB[2] + sB[3];
    float mu = S / (float)N;
    float var = (SS - S * S / (float)N) / (float)(N - 1);
    float thr = mu + gamma[0] * var;
    __syncthreads();
    float q = 0.f, c = 0.f;
    for (int i = tid; i < N; i += 256) {
        float d = yhat[i] - thr;
        if (d > 0.f) { q += d; c += 1.f; }
    }
    for (int off = 32; off; off >>= 1) {
        q += __shfl_down(q, off);
        c += __shfl_down(c, off);
    }
    if (lane == 0) { sA[wid] = q; sB[wid] = c; }
    __syncthreads();
    if (tid == 0) {
        float Q = sA[0] + sA[1] + sA[2] + sA[3];
        float Cnt = sB[0] + sB[1] + sB[2] + sB[3];
        float phat = Q / (Cnt + 1.f);
        out[0] = 0.5f * phat * (1.f + erff(phat * 0.70710678118654752f));
    }
}

extern "C" void kernel_launch(void* const* d_in, const int* in_sizes, int n_in,
                              void* d_out, int out_size, void* d_ws, size_t ws_size,
                              hipStream_t stream) {
    const float* z0   = (const float*)d_in[0];
    const float* z1   = (const float*)d_in[1];
    const float* Wemb = (const float*)d_in[2];
    const float* bemb = (const float*)d_in[3];
    const float* W1   = (const float*)d_in[4];
    const float* b1   = (const float*)d_in[5];
    const float* bn1g = (const float*)d_in[6];
    const float* bn1b = (const float*)d_in[7];
    const float* bn1m = (const float*)d_in[8];
    const float* bn1v = (const float*)d_in[9];
    const float* W2   = (const float*)d_in[10];
    const float* b2   = (const float*)d_in[11];
    const float* bn2g = (const float*)d_in[12];
    const float* bn2b = (const float*)d_in[13];
    const float* bn2m = (const float*)d_in[14];
    const float* bn2v = (const float*)d_in[15];
    const float* gam  = (const float*)d_in[16];

    float* ws   = (float*)d_ws;
    float* e0   = ws;                                    // 80,000 f32
    float* e1   = ws + 80000;                            // 80,000 f32
    __hip_bfloat16* Bmap = (__hip_bfloat16*)(ws + 160000);  // 50*PLANE bf16
    float* Cpart = ws + 160000 + 16483200;               // 10 x 640,000 f32
    float* Cbuf  = Cpart + 6400000;                      // 640,000 f32
    float* yhat  = Cbuf + 640000;                        // 7,921 f32
    unsigned short* Bh = (unsigned short*)(yhat + 8000); // 14,336 u16
    float* out  = (float*)d_out;

    kprep<<<688, 256, 0, stream>>>(z0, z1, Wemb, bemb, e0, e1, W1, Bh,
                                   (unsigned short*)Bmap);
    dim3 gi(100, 25);
    kinter<<<gi, 256, 0, stream>>>(e0, e1, Bh, b1, bn1g, bn1b, bn1m, bn1v, Bmap);
    dim3 gc(13, 13, 10);
    kconv<<<gc, 256, 0, stream>>>(Bmap, W2, Cpart);
    kreduce<<<(160000 + 255) / 256, 256, 0, stream>>>(Cpart, b2, bn2g, bn2b, bn2m, bn2v, Cbuf);
    kpool<<<(89 * 89 + 255) / 256, 256, 0, stream>>>(Cbuf, yhat);
    kfinal<<<1, 256, 0, stream>>>(yhat, gam, out);
}

// Round 10
// 177.391 us; speedup vs baseline: 1.5820x; 1.1737x over previous
//
#include <hip/hip_runtime.h>
#include <hip/hip_bf16.h>
#include <math.h>

#define EPS 1e-5f
#define ST 816                 // padded Bmap row stride (elems)
#define PLANE (816 * 808)      // padded plane elems

typedef _Float16 f16x8 __attribute__((ext_vector_type(8)));
typedef _Float16 h2 __attribute__((ext_vector_type(2)));
typedef float f32x4 __attribute__((ext_vector_type(4)));

__device__ __forceinline__ float elu_f(float x) {
    return x > 0.f ? x : __expf(x) - 1.f;
}

// ---- Merged prep: kembed (0..199) + kprepW (200..255) + kzero (256..688) + W2pack (689..691) ----
__global__ __launch_bounds__(256) void kprep(const float* __restrict__ z0,
                                             const float* __restrict__ z1,
                                             const float* __restrict__ Wemb,
                                             const float* __restrict__ bemb,
                                             float* __restrict__ e0,
                                             float* __restrict__ e1,
                                             const float* __restrict__ W1,
                                             unsigned short* __restrict__ Bh,
                                             unsigned short* __restrict__ Bmap,
                                             const float* __restrict__ W2,
                                             unsigned short* __restrict__ Wq) {
    __shared__ float4 zs4[2048];  // 8 rows x 1024 floats (kembed only)
    int b = blockIdx.x;
    int tid = threadIdx.x;
    if (b < 200) {
        // ---- kembed ----
        int src = b & 1;
        int rowbase = (b >> 1) * 8;
        const float* z = src ? z1 : z0;
        float* e = src ? e1 : e0;
        const float4* zrow4 = reinterpret_cast<const float4*>(z + rowbase * 1024);
        for (int idx = tid; idx < 2048; idx += 256) zs4[idx] = zrow4[idx];
        __syncthreads();
        if (tid < 200) {
            int d = tid % 100;
            int half = tid / 100;
            const float4* w4 = reinterpret_cast<const float4*>(Wemb + d * 1024);
            float acc[4] = {0.f, 0.f, 0.f, 0.f};
            for (int k = 0; k < 256; k++) {
                float4 w = w4[k];
#pragma unroll
                for (int r = 0; r < 4; r++) {
                    float4 zv = zs4[(half * 4 + r) * 256 + k];
                    acc[r] = fmaf(w.x, zv.x, acc[r]);
                    acc[r] = fmaf(w.y, zv.y, acc[r]);
                    acc[r] = fmaf(w.z, zv.z, acc[r]);
                    acc[r] = fmaf(w.w, zv.w, acc[r]);
                }
            }
            float be = bemb[d];
#pragma unroll
            for (int r = 0; r < 4; r++) {
                e[(rowbase + half * 4 + r) * 100 + d] = elu_f(acc[r] + be);
            }
        }
    } else if (b < 256) {
        // ---- kprepW: pack W1 as fp16 B-fragments, d-interleaved K (k = 2d+term, K=224) ----
        int idx = (b - 200) * 256 + tid;   // 0..14335 exactly
        int i = idx & 7;
        int lane = (idx >> 3) & 63;
        int hf = (idx >> 9) & 3;
        int ks = idx >> 11;                // 0..6
        int h = hf * 16 + (lane & 15);
        int k = ks * 32 + (lane >> 4) * 8 + i;
        int d = k >> 1;
        int term = k & 1;
        float val = (d < 100 && h < 50) ? W1[h * 200 + term * 100 + d] : 0.f;
        _Float16 hv = (_Float16)val;
        Bh[idx] = __builtin_bit_cast(unsigned short, hv);
    } else if (b < 689) {
        // ---- kzero (vectorized): zero halo borders of padded Bmap ----
        // per plane: 6 full rows (102 uint4) + 800 rows x 2 side uint4 = 2212 uint4
        int idx = (b - 256) * 256 + tid;
        if (idx < 110600) {
            int h = idx / 2212, q = idx % 2212;
            int row, colv;
            if (q < 612) {
                int rr = q / 102;
                colv = q - rr * 102;
                row = rr < 3 ? rr : 800 + rr;
            } else {
                int q2 = q - 612;
                row = 3 + (q2 >> 1);
                colv = (q2 & 1) ? 101 : 0;
            }
            uint4 zz = {0, 0, 0, 0};
            *(uint4*)&Bmap[(size_t)h * PLANE + (size_t)row * ST + colv * 8] = zz;
        }
    } else {
        // ---- W2 pack: dual-alignment fp16 weight quads for dot2 conv ----
        // item = h*14 + lay*7 + di -> 8 fp16 (uint4)
        // lay0 (even): (w0,w1),(w2,w3),(w4,w5),(w6,0)
        // lay1 (odd) : (0,w0),(w1,w2),(w3,w4),(w5,w6)
        int idx = (b - 689) * 256 + tid;
        if (idx < 700) {
            int h = idx / 14, rem = idx % 14;
            int lay = rem / 7, di = rem % 7;
            const float* wsrc = W2 + h * 49 + di * 7;
            unsigned short wf[8];
            if (lay == 0) {
#pragma unroll
                for (int t = 0; t < 7; t++)
                    wf[t] = __builtin_bit_cast(unsigned short, (_Float16)wsrc[t]);
                wf[7] = 0;
            } else {
                wf[0] = 0;
#pragma unroll
                for (int t = 0; t < 7; t++)
                    wf[t + 1] = __builtin_bit_cast(unsigned short, (_Float16)wsrc[t]);
            }
            *(uint4*)&Wq[idx * 8] = *(uint4*)wf;
        }
    }
}

// ---------------- Kernel 2: interaction GEMM via MFMA (fp16) ----------------
// grid (100,25), block 256 = 4 waves. Tile 8 i x 32 j. Bmap stored fp16.
__global__ __launch_bounds__(256) void kinter(const float* __restrict__ e0,
                                              const float* __restrict__ e1,
                                              const unsigned short* __restrict__ Bh,
                                              const float* __restrict__ b1,
                                              const float* __restrict__ g1,
                                              const float* __restrict__ bb1,
                                              const float* __restrict__ m1,
                                              const float* __restrict__ v1,
                                              unsigned short* __restrict__ Bmap) {
    __shared__ float e0s[8][116];
    __shared__ float e1s[32][116];
    int i0 = blockIdx.x * 8, j0 = blockIdx.y * 32;
    int tid = threadIdx.x;
    for (int idx = tid; idx < 40 * 116; idx += 256) {
        int r = idx / 116, c = idx % 116;
        float v = 0.f;
        if (c < 100) {
            v = (r < 8) ? e0[(i0 + r) * 100 + c] : e1[(j0 + r - 8) * 100 + c];
        }
        if (r < 8) e0s[r][c] = v;
        else e1s[r - 8][c] = v;
    }
    __syncthreads();

    int lane = tid & 63;
    int wid = tid >> 6;
    int g = lane >> 4;        // k-subchunk 0..3
    int jrow = lane & 15;     // A-row = j within frag

    f32x4 acc[2][2][4] = {};  // [fl][jf][hf]

    for (int ks = 0; ks < 7; ++ks) {
        f16x8 b[4];
#pragma unroll
        for (int hf = 0; hf < 4; ++hf) {
            int fidx = ((ks * 4 + hf) * 64 + lane) * 8;
            b[hf] = __builtin_bit_cast(f16x8, *(const uint4*)(Bh + fidx));
        }
        int d0 = ks * 16 + g * 4;
        float4 x0v[2];
        x0v[0] = *(const float4*)&e0s[wid * 2 + 0][d0];
        x0v[1] = *(const float4*)&e0s[wid * 2 + 1][d0];
#pragma unroll
        for (int jf = 0; jf < 2; ++jf) {
            float4 x1 = *(const float4*)&e1s[jf * 16 + jrow][d0];
#pragma unroll
            for (int fl = 0; fl < 2; ++fl) {
                float4 x0 = x0v[fl];
                unsigned int u0 = __builtin_bit_cast(unsigned int,
                    __builtin_amdgcn_cvt_pkrtz(fabsf(x0.x - x1.x), x0.x * x1.x));
                unsigned int u1 = __builtin_bit_cast(unsigned int,
                    __builtin_amdgcn_cvt_pkrtz(fabsf(x0.y - x1.y), x0.y * x1.y));
                unsigned int u2 = __builtin_bit_cast(unsigned int,
                    __builtin_amdgcn_cvt_pkrtz(fabsf(x0.z - x1.z), x0.z * x1.z));
                unsigned int u3 = __builtin_bit_cast(unsigned int,
                    __builtin_amdgcn_cvt_pkrtz(fabsf(x0.w - x1.w), x0.w * x1.w));
                uint4 au = {u0, u1, u2, u3};
                f16x8 a = __builtin_bit_cast(f16x8, au);
#pragma unroll
                for (int hf = 0; hf < 4; ++hf) {
                    acc[fl][jf][hf] = __builtin_amdgcn_mfma_f32_16x16x32_f16(
                        a, b[hf], acc[fl][jf][hf], 0, 0, 0);
                }
            }
        }
    }

    int hl = lane & 15;
#pragma unroll
    for (int hf = 0; hf < 4; ++hf) {
        int h = hf * 16 + hl;
        bool ok = h < 50;
        int hc = ok ? h : 0;
        float bnb = b1[hc];
        float sc = g1[hc] * rsqrtf(v1[hc] + EPS);
        float off = bb1[hc] - m1[hc] * sc;
#pragma unroll
        for (int fl = 0; fl < 2; ++fl) {
            int i = i0 + wid * 2 + fl;
#pragma unroll
            for (int jf = 0; jf < 2; ++jf) {
                int j = j0 + jf * 16 + g * 4;
                f32x4 a = acc[fl][jf][hf];
                unsigned short o[4];
#pragma unroll
                for (int r = 0; r < 4; ++r) {
                    float x = a[r] + bnb;
                    x = elu_f(x);
                    x = fmaf(x, sc, off);
                    x = elu_f(x);
                    o[r] = __builtin_bit_cast(unsigned short, (_Float16)x);  // fp16 now
                }
                if (ok) {
                    *(ushort4*)&Bmap[(size_t)h * PLANE + (size_t)(i + 3) * ST + (j + 8)] =
                        *(ushort4*)o;
                }
            }
        }
    }
}

// ---------------- Kernel 3: 7x7 conv via v_dot2_f32_f16, fp16 LDS tile ----------------
// grid (13,13,10); 256 thr as 16x16, 4x4 outputs/thread. tile[2][70][80] fp16 (22.4KB).
__global__ __launch_bounds__(256) void kconv(const unsigned short* __restrict__ Bmap,
                                             const unsigned short* __restrict__ Wq,
                                             float* __restrict__ Cpart) {
    __shared__ unsigned short tile[2][70][80];
    int bx = blockIdx.x, by = blockIdx.y, zc = blockIdx.z;
    int h0 = zc * 5;
    int tid = threadIdx.x;
    int lx = tid & 15, ly = tid >> 4;

    // staging: 70 rows x 10 uint4 (80 fp16) = 700 slots; 3 per thread
    int u0 = tid, u1 = tid + 256, u2 = tid + 512;
    int r0 = u0 / 10, k0 = u0 - r0 * 10;
    int r1 = u1 / 10, k1 = u1 - r1 * 10;
    int r2 = u2 / 10, k2 = u2 - r2 * 10;
    bool has2 = (u2 < 700);
    const unsigned short* base = Bmap + (size_t)h0 * PLANE;
    size_t o0 = (size_t)(64 * by + r0) * ST + 64 * bx + 8 * k0;
    size_t o1 = (size_t)(64 * by + r1) * ST + 64 * bx + 8 * k1;
    size_t o2 = (size_t)(64 * by + r2) * ST + 64 * bx + 8 * k2;

    // ch0 -> buf0
    *(uint4*)&tile[0][r0][8 * k0] = *(const uint4*)(base + o0);
    *(uint4*)&tile[0][r1][8 * k1] = *(const uint4*)(base + o1);
    if (has2) *(uint4*)&tile[0][r2][8 * k2] = *(const uint4*)(base + o2);
    // preload ch1 regs
    uint4 s0 = *(const uint4*)(base + PLANE + o0);
    uint4 s1 = *(const uint4*)(base + PLANE + o1);
    uint4 s2 = has2 ? *(const uint4*)(base + PLANE + o2) : uint4{0, 0, 0, 0};

    float acc[4][4] = {};
    for (int hh = 0; hh < 5; ++hh) {
        int cur = hh & 1;
        __syncthreads();
        if (hh < 4) {
            *(uint4*)&tile[cur ^ 1][r0][8 * k0] = s0;
            *(uint4*)&tile[cur ^ 1][r1][8 * k1] = s1;
            if (has2) *(uint4*)&tile[cur ^ 1][r2][8 * k2] = s2;
            if (hh < 3) {
                const unsigned short* nb = base + (size_t)(hh + 2) * PLANE;
                s0 = *(const uint4*)(nb + o0);
                s1 = *(const uint4*)(nb + o1);
                if (has2) s2 = *(const uint4*)(nb + o2);
            }
        }
        // weights (uniform): even/odd half2 quads
        h2 we[7][4], wo[7][4];
        {
            const uint4* wv = (const uint4*)Wq + (size_t)(h0 + hh) * 14;
#pragma unroll
            for (int di = 0; di < 7; ++di) {
                uint4 a = wv[di];       // even layout
                we[di][0] = __builtin_bit_cast(h2, a.x);
                we[di][1] = __builtin_bit_cast(h2, a.y);
                we[di][2] = __builtin_bit_cast(h2, a.z);
                we[di][3] = __builtin_bit_cast(h2, a.w);
                uint4 c = wv[7 + di];   // odd layout
                wo[di][0] = __builtin_bit_cast(h2, c.x);
                wo[di][1] = __builtin_bit_cast(h2, c.y);
                wo[di][2] = __builtin_bit_cast(h2, c.z);
                wo[di][3] = __builtin_bit_cast(h2, c.w);
            }
        }
#pragma unroll
        for (int r = 0; r < 10; ++r) {
            const unsigned int* trow = (const unsigned int*)&tile[cur][4 * ly + r][0];
            int mb = 2 * lx + 2;
            uint2 da = *(const uint2*)&trow[mb];       // q0,q1
            uint2 db = *(const uint2*)&trow[mb + 2];   // q2,q3
            uint2 dc = *(const uint2*)&trow[mb + 4];   // q4,q5
            h2 q0 = __builtin_bit_cast(h2, da.x), q1 = __builtin_bit_cast(h2, da.y);
            h2 q2 = __builtin_bit_cast(h2, db.x), q3 = __builtin_bit_cast(h2, db.y);
            h2 q4 = __builtin_bit_cast(h2, dc.x), q5 = __builtin_bit_cast(h2, dc.y);
#pragma unroll
            for (int rr = 0; rr < 4; ++rr) {
                int di = r - rr;
                if (di < 0 || di > 6) continue;
                acc[rr][0] = __builtin_amdgcn_fdot2(q0, wo[di][0],
                             __builtin_amdgcn_fdot2(q1, wo[di][1],
                             __builtin_amdgcn_fdot2(q2, wo[di][2],
                             __builtin_amdgcn_fdot2(q3, wo[di][3], acc[rr][0], false), false), false), false);
                acc[rr][1] = __builtin_amdgcn_fdot2(q1, we[di][0],
                             __builtin_amdgcn_fdot2(q2, we[di][1],
                             __builtin_amdgcn_fdot2(q3, we[di][2],
                             __builtin_amdgcn_fdot2(q4, we[di][3], acc[rr][1], false), false), false), false);
                acc[rr][2] = __builtin_amdgcn_fdot2(q1, wo[di][0],
                             __builtin_amdgcn_fdot2(q2, wo[di][1],
                             __builtin_amdgcn_fdot2(q3, wo[di][2],
                             __builtin_amdgcn_fdot2(q4, wo[di][3], acc[rr][2], false), false), false), false);
                acc[rr][3] = __builtin_amdgcn_fdot2(q2, we[di][0],
                             __builtin_amdgcn_fdot2(q3, we[di][1],
                             __builtin_amdgcn_fdot2(q4, we[di][2],
                             __builtin_amdgcn_fdot2(q5, we[di][3], acc[rr][3], false), false), false), false);
            }
        }
    }
    int j = 64 * bx + 4 * lx;
    if (j < 800) {
#pragma unroll
        for (int rr = 0; rr < 4; ++rr) {
            int i = 64 * by + 4 * ly + rr;
            if (i < 800)
                *(float4*)&Cpart[(size_t)zc * 640000 + (size_t)i * 800 + j] =
                    *(float4*)acc[rr];
        }
    }
}

// ---------------- Kernel 3b: reduce partials + bias + bn2 ----------------
__global__ __launch_bounds__(256) void kreduce(const float* __restrict__ Cpart,
                                               const float* __restrict__ b2,
                                               const float* __restrict__ g2,
                                               const float* __restrict__ bb2,
                                               const float* __restrict__ m2,
                                               const float* __restrict__ v2,
                                               float* __restrict__ C) {
    int idx = blockIdx.x * 256 + threadIdx.x;
    if (idx >= 160000) return;
    float s2 = g2[0] * rsqrtf(v2[0] + EPS);
    float t2 = bb2[0] - m2[0] * s2;
    float bias = b2[0];
    float4 s = ((const float4*)Cpart)[idx];
#pragma unroll
    for (int z = 1; z < 10; z++) {
        float4 p = ((const float4*)(Cpart + (size_t)z * 640000))[idx];
        s.x += p.x; s.y += p.y; s.z += p.z; s.w += p.w;
    }
    s.x = (s.x + bias) * s2 + t2;
    s.y = (s.y + bias) * s2 + t2;
    s.z = (s.z + bias) * s2 + t2;
    s.w = (s.w + bias) * s2 + t2;
    ((float4*)C)[idx] = s;
}

// ---------------- Kernel 4: 9x9/9 maxpool with pad 4 -> yhat (89x89) ----------------
__global__ __launch_bounds__(256) void kpool(const float* __restrict__ C,
                                             float* __restrict__ yhat) {
    int idx = blockIdx.x * 256 + threadIdx.x;
    if (idx >= 89 * 89) return;
    int oy = idx / 89, ox = idx % 89;
    float mx = -INFINITY;
    int y0 = oy * 9 - 4, x0 = ox * 9 - 4;
    for (int dy = 0; dy < 9; dy++) {
        int y = y0 + dy;
        if (y < 0 || y >= 800) continue;
        for (int dx = 0; dx < 9; dx++) {
            int x = x0 + dx;
            if (x < 0 || x >= 800) continue;
            mx = fmaxf(mx, C[y * 800 + x]);
        }
    }
    yhat[idx] = mx;
}

// ---------------- Kernel 5: mean/var -> Q -> phat -> gelu ----------------
__global__ __launch_bounds__(256) void kfinal(const float* __restrict__ yhat,
                                              const float* __restrict__ gamma,
                                              float* __restrict__ out) {
    const int N = 89 * 89;
    __shared__ float sA[4], sB[4];
    int tid = threadIdx.x;
    int wid = tid >> 6, lane = tid & 63;
    float s = 0.f, ss = 0.f;
    for (int i = tid; i < N; i += 256) {
        float y = yhat[i];
        s += y;
        ss = fmaf(y, y, ss);
    }
    for (int off = 32; off; off >>= 1) {
        s += __shfl_down(s, off);
        ss += __shfl_down(ss, off);
    }
    if (lane == 0) { sA[wid] = s; sB[wid] = ss; }
    __syncthreads();
    float S = sA[0] + sA[1] + sA[2] + sA[3];
    float SS = sB[0] + sB[1] + sB[2] + sB[3];
    float mu = S / (float)N;
    float var = (SS - S * S / (float)N) / (float)(N - 1);
    float thr = mu + gamma[0] * var;
    __syncthreads();
    float q = 0.f, c = 0.f;
    for (int i = tid; i < N; i += 256) {
        float d = yhat[i] - thr;
        if (d > 0.f) { q += d; c += 1.f; }
    }
    for (int off = 32; off; off >>= 1) {
        q += __shfl_down(q, off);
        c += __shfl_down(c, off);
    }
    if (lane == 0) { sA[wid] = q; sB[wid] = c; }
    __syncthreads();
    if (tid == 0) {
        float Q = sA[0] + sA[1] + sA[2] + sA[3];
        float Cnt = sB[0] + sB[1] + sB[2] + sB[3];
        float phat = Q / (Cnt + 1.f);
        out[0] = 0.5f * phat * (1.f + erff(phat * 0.70710678118654752f));
    }
}

extern "C" void kernel_launch(void* const* d_in, const int* in_sizes, int n_in,
                              void* d_out, int out_size, void* d_ws, size_t ws_size,
                              hipStream_t stream) {
    const float* z0   = (const float*)d_in[0];
    const float* z1   = (const float*)d_in[1];
    const float* Wemb = (const float*)d_in[2];
    const float* bemb = (const float*)d_in[3];
    const float* W1   = (const float*)d_in[4];
    const float* b1   = (const float*)d_in[5];
    const float* bn1g = (const float*)d_in[6];
    const float* bn1b = (const float*)d_in[7];
    const float* bn1m = (const float*)d_in[8];
    const float* bn1v = (const float*)d_in[9];
    const float* W2   = (const float*)d_in[10];
    const float* b2   = (const float*)d_in[11];
    const float* bn2g = (const float*)d_in[12];
    const float* bn2b = (const float*)d_in[13];
    const float* bn2m = (const float*)d_in[14];
    const float* bn2v = (const float*)d_in[15];
    const float* gam  = (const float*)d_in[16];

    float* ws   = (float*)d_ws;
    float* e0   = ws;                                    // 80,000 f32
    float* e1   = ws + 80000;                            // 80,000 f32
    unsigned short* Bmap = (unsigned short*)(ws + 160000);  // 50*PLANE fp16
    float* Cpart = ws + 160000 + 16483200;               // 10 x 640,000 f32
    float* Cbuf  = Cpart + 6400000;                      // 640,000 f32
    float* yhat  = Cbuf + 640000;                        // 7,921 f32
    unsigned short* Bh = (unsigned short*)(yhat + 8000); // 14,336 u16
    unsigned short* Wq = Bh + 14336;                     // 5,600 u16 (700 x uint4)
    float* out  = (float*)d_out;

    kprep<<<692, 256, 0, stream>>>(z0, z1, Wemb, bemb, e0, e1, W1, Bh,
                                   Bmap, W2, Wq);
    dim3 gi(100, 25);
    kinter<<<gi, 256, 0, stream>>>(e0, e1, Bh, b1, bn1g, bn1b, bn1m, bn1v, Bmap);
    dim3 gc(13, 13, 10);
    kconv<<<gc, 256, 0, stream>>>(Bmap, Wq, Cpart);
    kreduce<<<(160000 + 255) / 256, 256, 0, stream>>>(Cpart, b2, bn2g, bn2b, bn2m, bn2v, Cbuf);
    kpool<<<(89 * 89 + 255) / 256, 256, 0, stream>>>(Cbuf, yhat);
    kfinal<<<1, 256, 0, stream>>>(yhat, gam, out);
}

// Round 11
// 168.415 us; speedup vs baseline: 1.6663x; 1.0533x over previous
//
#include <hip/hip_runtime.h>
#include <hip/hip_bf16.h>
#include <math.h>

#define EPS 1e-5f
#define ST 896                   // padded Bmap row stride (fp16 elems), 64B-multiple
#define PLANE (896 * 806)        // padded plane elems (3+800+3 rows)
#define PLANE4 (PLANE / 8)       // uint4 per plane = 90272

typedef _Float16 f16x8 __attribute__((ext_vector_type(8)));
typedef _Float16 h2 __attribute__((ext_vector_type(2)));
typedef float f32x4 __attribute__((ext_vector_type(4)));

__device__ __forceinline__ float elu_f(float x) {
    return x > 0.f ? x : __expf(x) - 1.f;
}
__device__ __forceinline__ unsigned short f16b(float x) {
    return __builtin_bit_cast(unsigned short, (_Float16)x);
}

// ---- Merged prep: kembed (b<400) + kprepW (400..463) + kzero (464..1532) + W2pack (1533..1535) ----
// e stored fp16, rows padded to 112 (d in [100,112) = 0).
__global__ __launch_bounds__(256) void kprep(const float* __restrict__ z0,
                                             const float* __restrict__ z1,
                                             const float* __restrict__ Wemb,
                                             const float* __restrict__ bemb,
                                             unsigned short* __restrict__ e0h,
                                             unsigned short* __restrict__ e1h,
                                             const float* __restrict__ W1,
                                             unsigned short* __restrict__ Bh,
                                             unsigned short* __restrict__ Bmap,
                                             const float* __restrict__ W2,
                                             unsigned short* __restrict__ Wq) {
    __shared__ float4 zs4[1024];  // 4 rows x 1024 floats
    int b = blockIdx.x;
    int tid = threadIdx.x;
    if (b < 400) {
        // ---- kembed: 4 rows per block ----
        int src = b & 1;
        int rowbase = (b >> 1) * 4;
        const float* z = src ? z1 : z0;
        unsigned short* e = src ? e1h : e0h;
        const float4* zrow4 = reinterpret_cast<const float4*>(z + rowbase * 1024);
        for (int idx = tid; idx < 1024; idx += 256) zs4[idx] = zrow4[idx];
        __syncthreads();
        if (tid < 200) {
            int d = tid % 100;
            int half = tid / 100;      // 2 rows each
            const float4* w4 = reinterpret_cast<const float4*>(Wemb + d * 1024);
            float a0 = 0.f, a1 = 0.f;
            for (int k = 0; k < 256; k++) {
                float4 w = w4[k];
                float4 za = zs4[(half * 2 + 0) * 256 + k];
                float4 zb = zs4[(half * 2 + 1) * 256 + k];
                a0 = fmaf(w.x, za.x, a0); a0 = fmaf(w.y, za.y, a0);
                a0 = fmaf(w.z, za.z, a0); a0 = fmaf(w.w, za.w, a0);
                a1 = fmaf(w.x, zb.x, a1); a1 = fmaf(w.y, zb.y, a1);
                a1 = fmaf(w.z, zb.z, a1); a1 = fmaf(w.w, zb.w, a1);
            }
            float be = bemb[d];
            e[(rowbase + half * 2 + 0) * 112 + d] = f16b(elu_f(a0 + be));
            e[(rowbase + half * 2 + 1) * 112 + d] = f16b(elu_f(a1 + be));
        } else if (tid < 248) {
            int q = tid - 200;               // 4 rows x 12 pad slots
            int row = q / 12, pd = q % 12;
            (src ? e1h : e0h)[(rowbase + row) * 112 + 100 + pd] = 0;
        }
    } else if (b < 464) {
        // ---- kprepW: fp16 B-fragments; K=256: k<128 dif(d=k), k>=128 mul(d=k-128) ----
        int idx = (b - 400) * 256 + tid;     // 0..16383
        int i = idx & 7;
        int lane = (idx >> 3) & 63;
        int hf = (idx >> 9) & 3;
        int ks = idx >> 11;                  // 0..7
        int h = hf * 16 + (lane & 15);
        int k = ks * 32 + (lane >> 4) * 8 + i;
        int term = k >> 7;
        int d = k & 127;
        float val = (d < 100 && h < 50) ? W1[h * 200 + term * 100 + d] : 0.f;
        Bh[idx] = f16b(val);
    } else if (b < 1533) {
        // ---- kzero: halo borders of padded Bmap (uint4) ----
        // per plane: 6 full rows (112 uint4) + 800 rows x {col 3, cols 104..108} = 5472 uint4
        int idx = (b - 464) * 256 + tid;
        if (idx < 273600) {
            int h = idx / 5472, q = idx % 5472;
            int row, colv;
            if (q < 672) {
                int rr = q / 112;
                colv = q - rr * 112;
                row = rr < 3 ? rr : 800 + rr;
            } else {
                int q2 = q - 672;
                row = 3 + q2 / 6;
                int s = q2 % 6;
                colv = (s == 0) ? 3 : 103 + s;
            }
            uint4 zz = {0, 0, 0, 0};
            ((uint4*)Bmap)[(size_t)h * PLANE4 + row * 112 + colv] = zz;
        }
    } else {
        // ---- W2 pack: dual-alignment fp16 weight quads for dot2 conv ----
        int idx = (b - 1533) * 256 + tid;
        if (idx < 700) {
            int h = idx / 14, rem = idx % 14;
            int lay = rem / 7, di = rem % 7;
            const float* wsrc = W2 + h * 49 + di * 7;
            unsigned short wf[8];
            if (lay == 0) {
#pragma unroll
                for (int t = 0; t < 7; t++) wf[t] = f16b(wsrc[t]);
                wf[7] = 0;
            } else {
                wf[0] = 0;
#pragma unroll
                for (int t = 0; t < 7; t++) wf[t + 1] = f16b(wsrc[t]);
            }
            *(uint4*)&Wq[idx * 8] = *(uint4*)wf;
        }
    }
}

// ---------------- Kernel 2: interaction GEMM via MFMA (fp16, split-K 256) ----------------
// grid (100,25), 256 thr = 4 waves. Tile 8 i x 32 j. fp16 e in LDS (stride 120).
__global__ __launch_bounds__(256) void kinter(const unsigned short* __restrict__ e0h,
                                              const unsigned short* __restrict__ e1h,
                                              const unsigned short* __restrict__ Bh,
                                              const float* __restrict__ b1,
                                              const float* __restrict__ g1,
                                              const float* __restrict__ bb1,
                                              const float* __restrict__ m1,
                                              const float* __restrict__ v1,
                                              unsigned short* __restrict__ Bmap) {
    __shared__ unsigned short e0s[8][120];
    __shared__ unsigned short e1s[32][120];
    int i0 = blockIdx.x * 8, j0 = blockIdx.y * 32;
    int tid = threadIdx.x;
    // stage 40 rows x 15 uint4 (last uint4 zero -> cols 112..119 defined)
    for (int idx = tid; idx < 600; idx += 256) {
        int r = idx / 15, c = idx % 15;
        uint4 v = {0, 0, 0, 0};
        if (c < 14)
            v = (r < 8) ? *(const uint4*)(e0h + (i0 + r) * 112 + c * 8)
                        : *(const uint4*)(e1h + (j0 + r - 8) * 112 + c * 8);
        if (r < 8) *(uint4*)&e0s[r][c * 8] = v;
        else *(uint4*)&e1s[r - 8][c * 8] = v;
    }
    __syncthreads();

    int lane = tid & 63;
    int wid = tid >> 6;
    int g = lane >> 4;        // k-subchunk 0..3
    int jrow = lane & 15;     // A-row = j within frag

    f32x4 acc[2][2][4] = {};  // [fl][jf][hf]

#pragma unroll
    for (int ks = 0; ks < 8; ++ks) {
        f16x8 b[4];
#pragma unroll
        for (int hf = 0; hf < 4; ++hf) {
            int fidx = ((ks * 4 + hf) * 64 + lane) * 8;
            b[hf] = __builtin_bit_cast(f16x8, *(const uint4*)(Bh + fidx));
        }
        int d0 = (ks & 3) * 32 + g * 8;
        d0 = d0 > 112 ? 112 : d0;            // clamp: pad region is all zeros
        f16x8 x0v[2];
        x0v[0] = *(const f16x8*)&e0s[wid * 2 + 0][d0];
        x0v[1] = *(const f16x8*)&e0s[wid * 2 + 1][d0];
#pragma unroll
        for (int jf = 0; jf < 2; ++jf) {
            f16x8 x1 = *(const f16x8*)&e1s[jf * 16 + jrow][d0];
#pragma unroll
            for (int fl = 0; fl < 2; ++fl) {
                f16x8 a;
                if (ks < 4) {                 // dif half (compile-time branch)
                    f16x8 dd = x0v[fl] - x1;
                    uint4 u = __builtin_bit_cast(uint4, dd);
                    u.x &= 0x7FFF7FFFu; u.y &= 0x7FFF7FFFu;
                    u.z &= 0x7FFF7FFFu; u.w &= 0x7FFF7FFFu;
                    a = __builtin_bit_cast(f16x8, u);
                } else {                      // mul half
                    a = x0v[fl] * x1;
                }
#pragma unroll
                for (int hf = 0; hf < 4; ++hf) {
                    acc[fl][jf][hf] = __builtin_amdgcn_mfma_f32_16x16x32_f16(
                        a, b[hf], acc[fl][jf][hf], 0, 0, 0);
                }
            }
        }
    }

    // epilogue: D[row=j][col=h]; lane (g,hl): rows j = jf*16 + g*4 + r, col h = hf*16+hl
    int hl = lane & 15;
#pragma unroll
    for (int hf = 0; hf < 4; ++hf) {
        int h = hf * 16 + hl;
        bool ok = h < 50;
        int hc = ok ? h : 0;
        float bnb = b1[hc];
        float sc = g1[hc] * rsqrtf(v1[hc] + EPS);
        float off = bb1[hc] - m1[hc] * sc;
#pragma unroll
        for (int fl = 0; fl < 2; ++fl) {
            int i = i0 + wid * 2 + fl;
#pragma unroll
            for (int jf = 0; jf < 2; ++jf) {
                int j = j0 + jf * 16 + g * 4;
                f32x4 a = acc[fl][jf][hf];
                unsigned short o[4];
#pragma unroll
                for (int r = 0; r < 4; ++r) {
                    float x = a[r] + bnb;
                    x = elu_f(x);
                    x = fmaf(x, sc, off);
                    x = elu_f(x);
                    o[r] = f16b(x);
                }
                if (ok) {
                    // (h, i, j) at h*PLANE + (i+3)*ST + (j+32): 64B-line aligned per (h,i)
                    *(ushort4*)&Bmap[(size_t)h * PLANE + (size_t)(i + 3) * ST + (j + 32)] =
                        *(ushort4*)o;
                }
            }
        }
    }
}

// ---------------- Kernel 3: 7x7 conv via v_dot2_f32_f16, fp16 LDS, dbuf ----------------
// grid (13,13,10); 256 thr as 16x16, 4x4 outputs/thread. tile[2][70][80] fp16.
__global__ __launch_bounds__(256) void kconv(const unsigned short* __restrict__ Bmap,
                                             const unsigned short* __restrict__ Wq,
                                             unsigned short* __restrict__ CpH) {
    __shared__ unsigned short tile[2][70][80];
    int bx = blockIdx.x, by = blockIdx.y, zc = blockIdx.z;
    int h0 = zc * 5;
    int tid = threadIdx.x;
    int lx = tid & 15, ly = tid >> 4;

    int u0 = tid, u1 = tid + 256, u2 = tid + 512;
    int r0 = u0 / 10, k0 = u0 - r0 * 10;
    int r1 = u1 / 10, k1 = u1 - r1 * 10;
    int r2 = u2 / 10, k2 = u2 - r2 * 10;
    bool has2 = (u2 < 700);
    const unsigned short* base = Bmap + (size_t)h0 * PLANE;
    // tile covers padded cols [64bx+24, 64bx+104) = global j [64bx-8, 64bx+72)
    size_t o0 = (size_t)(64 * by + r0) * ST + 64 * bx + 24 + 8 * k0;
    size_t o1 = (size_t)(64 * by + r1) * ST + 64 * bx + 24 + 8 * k1;
    size_t o2 = (size_t)(64 * by + r2) * ST + 64 * bx + 24 + 8 * k2;

    *(uint4*)&tile[0][r0][8 * k0] = *(const uint4*)(base + o0);
    *(uint4*)&tile[0][r1][8 * k1] = *(const uint4*)(base + o1);
    if (has2) *(uint4*)&tile[0][r2][8 * k2] = *(const uint4*)(base + o2);
    uint4 s0 = *(const uint4*)(base + PLANE + o0);
    uint4 s1 = *(const uint4*)(base + PLANE + o1);
    uint4 s2 = has2 ? *(const uint4*)(base + PLANE + o2) : uint4{0, 0, 0, 0};

    float acc[4][4] = {};
    for (int hh = 0; hh < 5; ++hh) {
        int cur = hh & 1;
        __syncthreads();
        if (hh < 4) {
            *(uint4*)&tile[cur ^ 1][r0][8 * k0] = s0;
            *(uint4*)&tile[cur ^ 1][r1][8 * k1] = s1;
            if (has2) *(uint4*)&tile[cur ^ 1][r2][8 * k2] = s2;
            if (hh < 3) {
                const unsigned short* nb = base + (size_t)(hh + 2) * PLANE;
                s0 = *(const uint4*)(nb + o0);
                s1 = *(const uint4*)(nb + o1);
                if (has2) s2 = *(const uint4*)(nb + o2);
            }
        }
        h2 we[7][4], wo[7][4];
        {
            const uint4* wv = (const uint4*)Wq + (size_t)(h0 + hh) * 14;
#pragma unroll
            for (int di = 0; di < 7; ++di) {
                uint4 a = wv[di];
                we[di][0] = __builtin_bit_cast(h2, a.x);
                we[di][1] = __builtin_bit_cast(h2, a.y);
                we[di][2] = __builtin_bit_cast(h2, a.z);
                we[di][3] = __builtin_bit_cast(h2, a.w);
                uint4 c = wv[7 + di];
                wo[di][0] = __builtin_bit_cast(h2, c.x);
                wo[di][1] = __builtin_bit_cast(h2, c.y);
                wo[di][2] = __builtin_bit_cast(h2, c.z);
                wo[di][3] = __builtin_bit_cast(h2, c.w);
            }
        }
#pragma unroll
        for (int r = 0; r < 10; ++r) {
            const unsigned int* trow = (const unsigned int*)&tile[cur][4 * ly + r][0];
            int mb = 2 * lx + 2;
            uint2 da = *(const uint2*)&trow[mb];
            uint2 db = *(const uint2*)&trow[mb + 2];
            uint2 dc = *(const uint2*)&trow[mb + 4];
            h2 q0 = __builtin_bit_cast(h2, da.x), q1 = __builtin_bit_cast(h2, da.y);
            h2 q2 = __builtin_bit_cast(h2, db.x), q3 = __builtin_bit_cast(h2, db.y);
            h2 q4 = __builtin_bit_cast(h2, dc.x), q5 = __builtin_bit_cast(h2, dc.y);
#pragma unroll
            for (int rr = 0; rr < 4; ++rr) {
                int di = r - rr;
                if (di < 0 || di > 6) continue;
                acc[rr][0] = __builtin_amdgcn_fdot2(q0, wo[di][0],
                             __builtin_amdgcn_fdot2(q1, wo[di][1],
                             __builtin_amdgcn_fdot2(q2, wo[di][2],
                             __builtin_amdgcn_fdot2(q3, wo[di][3], acc[rr][0], false), false), false), false);
                acc[rr][1] = __builtin_amdgcn_fdot2(q1, we[di][0],
                             __builtin_amdgcn_fdot2(q2, we[di][1],
                             __builtin_amdgcn_fdot2(q3, we[di][2],
                             __builtin_amdgcn_fdot2(q4, we[di][3], acc[rr][1], false), false), false), false);
                acc[rr][2] = __builtin_amdgcn_fdot2(q1, wo[di][0],
                             __builtin_amdgcn_fdot2(q2, wo[di][1],
                             __builtin_amdgcn_fdot2(q3, wo[di][2],
                             __builtin_amdgcn_fdot2(q4, wo[di][3], acc[rr][2], false), false), false), false);
                acc[rr][3] = __builtin_amdgcn_fdot2(q2, we[di][0],
                             __builtin_amdgcn_fdot2(q3, we[di][1],
                             __builtin_amdgcn_fdot2(q4, we[di][2],
                             __builtin_amdgcn_fdot2(q5, we[di][3], acc[rr][3], false), false), false), false);
            }
        }
    }
    int j = 64 * bx + 4 * lx;
    if (j < 800) {
#pragma unroll
        for (int rr = 0; rr < 4; ++rr) {
            int i = 64 * by + 4 * ly + rr;
            if (i < 800) {
                unsigned short st[4];
#pragma unroll
                for (int cc = 0; cc < 4; ++cc) st[cc] = f16b(acc[rr][cc]);
                *(ushort4*)&CpH[(size_t)zc * 640000 + (size_t)i * 800 + j] =
                    *(ushort4*)st;
            }
        }
    }
}

// ---------------- Kernel 3b: reduce fp16 partials + bias + bn2 -> f32 C ----------------
__global__ __launch_bounds__(256) void kreduce(const unsigned short* __restrict__ CpH,
                                               const float* __restrict__ b2,
                                               const float* __restrict__ g2,
                                               const float* __restrict__ bb2,
                                               const float* __restrict__ m2,
                                               const float* __restrict__ v2,
                                               float* __restrict__ C) {
    int idx = blockIdx.x * 256 + threadIdx.x;   // uint4 index over 8 fp16
    if (idx >= 80000) return;
    float s2 = g2[0] * rsqrtf(v2[0] + EPS);
    float t2 = bb2[0] - m2[0] * s2;
    float bias = b2[0];
    float s[8] = {0.f, 0.f, 0.f, 0.f, 0.f, 0.f, 0.f, 0.f};
#pragma unroll
    for (int z = 0; z < 10; z++) {
        uint4 v = ((const uint4*)(CpH + (size_t)z * 640000))[idx];
        h2 p0 = __builtin_bit_cast(h2, v.x), p1 = __builtin_bit_cast(h2, v.y);
        h2 p2 = __builtin_bit_cast(h2, v.z), p3 = __builtin_bit_cast(h2, v.w);
        s[0] += (float)p0[0]; s[1] += (float)p0[1];
        s[2] += (float)p1[0]; s[3] += (float)p1[1];
        s[4] += (float)p2[0]; s[5] += (float)p2[1];
        s[6] += (float)p3[0]; s[7] += (float)p3[1];
    }
    float4 oa, ob;
    oa.x = (s[0] + bias) * s2 + t2; oa.y = (s[1] + bias) * s2 + t2;
    oa.z = (s[2] + bias) * s2 + t2; oa.w = (s[3] + bias) * s2 + t2;
    ob.x = (s[4] + bias) * s2 + t2; ob.y = (s[5] + bias) * s2 + t2;
    ob.z = (s[6] + bias) * s2 + t2; ob.w = (s[7] + bias) * s2 + t2;
    ((float4*)C)[idx * 2] = oa;
    ((float4*)C)[idx * 2 + 1] = ob;
}

// ---------------- Kernel 4: 9x9/9 maxpool with pad 4 -> yhat (89x89) ----------------
__global__ __launch_bounds__(256) void kpool(const float* __restrict__ C,
                                             float* __restrict__ yhat) {
    int idx = blockIdx.x * 256 + threadIdx.x;
    if (idx >= 89 * 89) return;
    int oy = idx / 89, ox = idx % 89;
    float mx = -INFINITY;
    int y0 = oy * 9 - 4, x0 = ox * 9 - 4;
    for (int dy = 0; dy < 9; dy++) {
        int y = y0 + dy;
        if (y < 0 || y >= 800) continue;
        for (int dx = 0; dx < 9; dx++) {
            int x = x0 + dx;
            if (x < 0 || x >= 800) continue;
            mx = fmaxf(mx, C[y * 800 + x]);
        }
    }
    yhat[idx] = mx;
}

// ---------------- Kernel 5: mean/var -> Q -> phat -> gelu ----------------
__global__ __launch_bounds__(256) void kfinal(const float* __restrict__ yhat,
                                              const float* __restrict__ gamma,
                                              float* __restrict__ out) {
    const int N = 89 * 89;
    __shared__ float sA[4], sB[4];
    int tid = threadIdx.x;
    int wid = tid >> 6, lane = tid & 63;
    float s = 0.f, ss = 0.f;
    for (int i = tid; i < N; i += 256) {
        float y = yhat[i];
        s += y;
        ss = fmaf(y, y, ss);
    }
    for (int off = 32; off; off >>= 1) {
        s += __shfl_down(s, off);
        ss += __shfl_down(ss, off);
    }
    if (lane == 0) { sA[wid] = s; sB[wid] = ss; }
    __syncthreads();
    float S = sA[0] + sA[1] + sA[2] + sA[3];
    float SS = sB[0] + sB[1] + sB[2] + sB[3];
    float mu = S / (float)N;
    float var = (SS - S * S / (float)N) / (float)(N - 1);
    float thr = mu + gamma[0] * var;
    __syncthreads();
    float q = 0.f, c = 0.f;
    for (int i = tid; i < N; i += 256) {
        float d = yhat[i] - thr;
        if (d > 0.f) { q += d; c += 1.f; }
    }
    for (int off = 32; off; off >>= 1) {
        q += __shfl_down(q, off);
        c += __shfl_down(c, off);
    }
    if (lane == 0) { sA[wid] = q; sB[wid] = c; }
    __syncthreads();
    if (tid == 0) {
        float Q = sA[0] + sA[1] + sA[2] + sA[3];
        float Cnt = sB[0] + sB[1] + sB[2] + sB[3];
        float phat = Q / (Cnt + 1.f);
        out[0] = 0.5f * phat * (1.f + erff(phat * 0.70710678118654752f));
    }
}

extern "C" void kernel_launch(void* const* d_in, const int* in_sizes, int n_in,
                              void* d_out, int out_size, void* d_ws, size_t ws_size,
                              hipStream_t stream) {
    const float* z0   = (const float*)d_in[0];
    const float* z1   = (const float*)d_in[1];
    const float* Wemb = (const float*)d_in[2];
    const float* bemb = (const float*)d_in[3];
    const float* W1   = (const float*)d_in[4];
    const float* b1   = (const float*)d_in[5];
    const float* bn1g = (const float*)d_in[6];
    const float* bn1b = (const float*)d_in[7];
    const float* bn1m = (const float*)d_in[8];
    const float* bn1v = (const float*)d_in[9];
    const float* W2   = (const float*)d_in[10];
    const float* b2   = (const float*)d_in[11];
    const float* bn2g = (const float*)d_in[12];
    const float* bn2b = (const float*)d_in[13];
    const float* bn2m = (const float*)d_in[14];
    const float* bn2v = (const float*)d_in[15];
    const float* gam  = (const float*)d_in[16];

    // layout (bytes): e0h 179200 | e1h 179200 | Bh 32768 | Wq 11200 | Bmap 72.2MB | CpH 12.8MB
    unsigned short* e0h  = (unsigned short*)d_ws;               // 800 x 112 fp16
    unsigned short* e1h  = e0h + 89600;
    unsigned short* Bh   = e1h + 89600;                         // 16,384 fp16
    unsigned short* Wq   = Bh + 16384;                          // 5,600 fp16
    unsigned short* Bmap = Wq + 5600;                           // 50 x PLANE fp16
    unsigned short* CpH  = Bmap + (size_t)50 * PLANE;           // 10 x 640,000 fp16
    float* Cbuf = (float*)Bmap;                                 // alias (Bmap dead after kconv)
    float* yhat = Cbuf + 640000;
    float* out  = (float*)d_out;

    kprep<<<1536, 256, 0, stream>>>(z0, z1, Wemb, bemb, e0h, e1h, W1, Bh,
                                    Bmap, W2, Wq);
    dim3 gi(100, 25);
    kinter<<<gi, 256, 0, stream>>>(e0h, e1h, Bh, b1, bn1g, bn1b, bn1m, bn1v, Bmap);
    dim3 gc(13, 13, 10);
    kconv<<<gc, 256, 0, stream>>>(Bmap, Wq, CpH);
    kreduce<<<(80000 + 255) / 256, 256, 0, stream>>>(CpH, b2, bn2g, bn2b, bn2m, bn2v, Cbuf);
    kpool<<<(89 * 89 + 255) / 256, 256, 0, stream>>>(Cbuf, yhat);
    kfinal<<<1, 256, 0, stream>>>(yhat, gam, out);
}

// Round 12
// 148.239 us; speedup vs baseline: 1.8931x; 1.1361x over previous
//
#include <hip/hip_runtime.h>
#include <hip/hip_bf16.h>
#include <math.h>

#define EPS 1e-5f
#define ST 896                   // padded Bmap row stride (fp16 elems), 64B-multiple
#define PLANE (896 * 806)        // padded plane elems (3+800+3 rows)
#define PLANE4 (PLANE / 8)       // uint4 per plane = 90272

typedef _Float16 f16x8 __attribute__((ext_vector_type(8)));
typedef _Float16 h2 __attribute__((ext_vector_type(2)));
typedef float f32x4 __attribute__((ext_vector_type(4)));

__device__ __forceinline__ float elu_f(float x) {
    return x > 0.f ? x : __expf(x) - 1.f;
}
__device__ __forceinline__ unsigned short f16b(float x) {
    return __builtin_bit_cast(unsigned short, (_Float16)x);
}

// ---- Merged prep ----
// b<100:      kembed via MFMA (16 z-rows/block, e fp16 rows padded to 112)
// 100..163:   kprepW (W1 -> fp16 B-fragments, K=256 split-K layout)
// 164..1232:  kzero  (halo borders of padded Bmap)
// 1233..1235: W2pack (dual-alignment fp16 weight quads)
__global__ __launch_bounds__(256) void kprep(const float* __restrict__ z0,
                                             const float* __restrict__ z1,
                                             const float* __restrict__ Wemb,
                                             const float* __restrict__ bemb,
                                             unsigned short* __restrict__ e0h,
                                             unsigned short* __restrict__ e1h,
                                             const float* __restrict__ W1,
                                             unsigned short* __restrict__ Bh,
                                             unsigned short* __restrict__ Bmap,
                                             const float* __restrict__ W2,
                                             unsigned short* __restrict__ Wq) {
    __shared__ unsigned short zls[16][1032];   // 16 z-rows fp16, padded stride
    int b = blockIdx.x;
    int tid = threadIdx.x;
    if (b < 100) {
        // ---- kembed MFMA: e[m][d] = elu(z[m][:] . Wemb[d][:] + bemb[d]) ----
        int src = b & 1;
        int rowbase = (b >> 1) * 16;
        const float* z = src ? z1 : z0;
        unsigned short* e = src ? e1h : e0h;
        const float4* zr4 = (const float4*)(z + rowbase * 1024);
        for (int idx = tid; idx < 4096; idx += 256) {
            int r = idx >> 8, c = idx & 255;
            float4 v = zr4[idx];
            unsigned int p0 = __builtin_bit_cast(unsigned int,
                __builtin_amdgcn_cvt_pkrtz(v.x, v.y));
            unsigned int p1 = __builtin_bit_cast(unsigned int,
                __builtin_amdgcn_cvt_pkrtz(v.z, v.w));
            uint2 pv = {p0, p1};
            *(uint2*)&zls[r][c * 4] = pv;
        }
        __syncthreads();
        int lane = tid & 63, wid = tid >> 6;
        int g = lane >> 4, rl = lane & 15;
        int mf0 = wid * 2;
        int nfrag = (wid < 3) ? 2 : 1;      // 7 d-frags over 4 waves
        f32x4 acc[2] = {};
        for (int ks = 0; ks < 32; ++ks) {
            f16x8 bz = *(const f16x8*)&zls[rl][ks * 32 + g * 8];
#pragma unroll
            for (int q = 0; q < 2; ++q) {
                if (q < nfrag) {
                    int d = (mf0 + q) * 16 + rl;
                    d = d > 99 ? 99 : d;
                    const float* wp = Wemb + d * 1024 + ks * 32 + g * 8;
                    float4 w0 = *(const float4*)wp;
                    float4 w1 = *(const float4*)(wp + 4);
                    uint4 au;
                    au.x = __builtin_bit_cast(unsigned int,
                        __builtin_amdgcn_cvt_pkrtz(w0.x, w0.y));
                    au.y = __builtin_bit_cast(unsigned int,
                        __builtin_amdgcn_cvt_pkrtz(w0.z, w0.w));
                    au.z = __builtin_bit_cast(unsigned int,
                        __builtin_amdgcn_cvt_pkrtz(w1.x, w1.y));
                    au.w = __builtin_bit_cast(unsigned int,
                        __builtin_amdgcn_cvt_pkrtz(w1.z, w1.w));
                    f16x8 a = __builtin_bit_cast(f16x8, au);
                    acc[q] = __builtin_amdgcn_mfma_f32_16x16x32_f16(a, bz, acc[q], 0, 0, 0);
                }
            }
        }
        // D: z-col = lane&15, d-row = (lane>>4)*4 + r  -> ushort4 store, pad d>=100 = 0
#pragma unroll
        for (int q = 0; q < 2; ++q) {
            if (q < nfrag) {
                int dbase = (mf0 + q) * 16 + g * 4;
                int zr = rowbase + rl;
                unsigned short o[4];
#pragma unroll
                for (int r = 0; r < 4; ++r) {
                    int d = dbase + r;
                    float be = bemb[d > 99 ? 99 : d];
                    float x = elu_f(acc[q][r] + be);
                    o[r] = (d < 100) ? f16b(x) : (unsigned short)0;
                }
                *(ushort4*)&e[zr * 112 + dbase] = *(ushort4*)o;
            }
        }
    } else if (b < 164) {
        // ---- kprepW: fp16 B-fragments; K=256: k<128 dif(d=k), k>=128 mul(d=k-128) ----
        int idx = (b - 100) * 256 + tid;     // 0..16383
        int i = idx & 7;
        int lane = (idx >> 3) & 63;
        int hf = (idx >> 9) & 3;
        int ks = idx >> 11;                  // 0..7
        int h = hf * 16 + (lane & 15);
        int k = ks * 32 + (lane >> 4) * 8 + i;
        int term = k >> 7;
        int d = k & 127;
        float val = (d < 100 && h < 50) ? W1[h * 200 + term * 100 + d] : 0.f;
        Bh[idx] = f16b(val);
    } else if (b < 1233) {
        // ---- kzero: halo borders of padded Bmap (uint4) ----
        int idx = (b - 164) * 256 + tid;
        if (idx < 273600) {
            int h = idx / 5472, q = idx % 5472;
            int row, colv;
            if (q < 672) {
                int rr = q / 112;
                colv = q - rr * 112;
                row = rr < 3 ? rr : 800 + rr;
            } else {
                int q2 = q - 672;
                row = 3 + q2 / 6;
                int s = q2 % 6;
                colv = (s == 0) ? 3 : 103 + s;
            }
            uint4 zz = {0, 0, 0, 0};
            ((uint4*)Bmap)[(size_t)h * PLANE4 + row * 112 + colv] = zz;
        }
    } else {
        // ---- W2 pack: dual-alignment fp16 weight quads for dot2 conv ----
        int idx = (b - 1233) * 256 + tid;
        if (idx < 700) {
            int h = idx / 14, rem = idx % 14;
            int lay = rem / 7, di = rem % 7;
            const float* wsrc = W2 + h * 49 + di * 7;
            unsigned short wf[8];
            if (lay == 0) {
#pragma unroll
                for (int t = 0; t < 7; t++) wf[t] = f16b(wsrc[t]);
                wf[7] = 0;
            } else {
                wf[0] = 0;
#pragma unroll
                for (int t = 0; t < 7; t++) wf[t + 1] = f16b(wsrc[t]);
            }
            *(uint4*)&Wq[idx * 8] = *(uint4*)wf;
        }
    }
}

// ---------------- Kernel 2: interaction GEMM via MFMA (fp16, split-K 256) ----------------
// grid (100,25), 256 thr = 4 waves. Tile 8 i x 32 j. fp16 e in LDS (stride 120).
__global__ __launch_bounds__(256) void kinter(const unsigned short* __restrict__ e0h,
                                              const unsigned short* __restrict__ e1h,
                                              const unsigned short* __restrict__ Bh,
                                              const float* __restrict__ b1,
                                              const float* __restrict__ g1,
                                              const float* __restrict__ bb1,
                                              const float* __restrict__ m1,
                                              const float* __restrict__ v1,
                                              unsigned short* __restrict__ Bmap) {
    __shared__ unsigned short e0s[8][120];
    __shared__ unsigned short e1s[32][120];
    int i0 = blockIdx.x * 8, j0 = blockIdx.y * 32;
    int tid = threadIdx.x;
    for (int idx = tid; idx < 600; idx += 256) {
        int r = idx / 15, c = idx % 15;
        uint4 v = {0, 0, 0, 0};
        if (c < 14)
            v = (r < 8) ? *(const uint4*)(e0h + (i0 + r) * 112 + c * 8)
                        : *(const uint4*)(e1h + (j0 + r - 8) * 112 + c * 8);
        if (r < 8) *(uint4*)&e0s[r][c * 8] = v;
        else *(uint4*)&e1s[r - 8][c * 8] = v;
    }
    __syncthreads();

    int lane = tid & 63;
    int wid = tid >> 6;
    int g = lane >> 4;
    int jrow = lane & 15;

    f32x4 acc[2][2][4] = {};

#pragma unroll
    for (int ks = 0; ks < 8; ++ks) {
        f16x8 b[4];
#pragma unroll
        for (int hf = 0; hf < 4; ++hf) {
            int fidx = ((ks * 4 + hf) * 64 + lane) * 8;
            b[hf] = __builtin_bit_cast(f16x8, *(const uint4*)(Bh + fidx));
        }
        int d0 = (ks & 3) * 32 + g * 8;
        d0 = d0 > 112 ? 112 : d0;
        f16x8 x0v[2];
        x0v[0] = *(const f16x8*)&e0s[wid * 2 + 0][d0];
        x0v[1] = *(const f16x8*)&e0s[wid * 2 + 1][d0];
#pragma unroll
        for (int jf = 0; jf < 2; ++jf) {
            f16x8 x1 = *(const f16x8*)&e1s[jf * 16 + jrow][d0];
#pragma unroll
            for (int fl = 0; fl < 2; ++fl) {
                f16x8 a;
                if (ks < 4) {
                    f16x8 dd = x0v[fl] - x1;
                    uint4 u = __builtin_bit_cast(uint4, dd);
                    u.x &= 0x7FFF7FFFu; u.y &= 0x7FFF7FFFu;
                    u.z &= 0x7FFF7FFFu; u.w &= 0x7FFF7FFFu;
                    a = __builtin_bit_cast(f16x8, u);
                } else {
                    a = x0v[fl] * x1;
                }
#pragma unroll
                for (int hf = 0; hf < 4; ++hf) {
                    acc[fl][jf][hf] = __builtin_amdgcn_mfma_f32_16x16x32_f16(
                        a, b[hf], acc[fl][jf][hf], 0, 0, 0);
                }
            }
        }
    }

    int hl = lane & 15;
#pragma unroll
    for (int hf = 0; hf < 4; ++hf) {
        int h = hf * 16 + hl;
        bool ok = h < 50;
        int hc = ok ? h : 0;
        float bnb = b1[hc];
        float sc = g1[hc] * rsqrtf(v1[hc] + EPS);
        float off = bb1[hc] - m1[hc] * sc;
#pragma unroll
        for (int fl = 0; fl < 2; ++fl) {
            int i = i0 + wid * 2 + fl;
#pragma unroll
            for (int jf = 0; jf < 2; ++jf) {
                int j = j0 + jf * 16 + g * 4;
                f32x4 a = acc[fl][jf][hf];
                unsigned short o[4];
#pragma unroll
                for (int r = 0; r < 4; ++r) {
                    float x = a[r] + bnb;
                    x = elu_f(x);
                    x = fmaf(x, sc, off);
                    x = elu_f(x);
                    o[r] = f16b(x);
                }
                if (ok) {
                    *(ushort4*)&Bmap[(size_t)h * PLANE + (size_t)(i + 3) * ST + (j + 32)] =
                        *(ushort4*)o;
                }
            }
        }
    }
}

// ---------------- Kernel 3: 7x7 conv via v_dot2_f32_f16, fp16 LDS, dbuf ----------------
__global__ __launch_bounds__(256) void kconv(const unsigned short* __restrict__ Bmap,
                                             const unsigned short* __restrict__ Wq,
                                             unsigned short* __restrict__ CpH) {
    __shared__ unsigned short tile[2][70][80];
    int bx = blockIdx.x, by = blockIdx.y, zc = blockIdx.z;
    int h0 = zc * 5;
    int tid = threadIdx.x;
    int lx = tid & 15, ly = tid >> 4;

    int u0 = tid, u1 = tid + 256, u2 = tid + 512;
    int r0 = u0 / 10, k0 = u0 - r0 * 10;
    int r1 = u1 / 10, k1 = u1 - r1 * 10;
    int r2 = u2 / 10, k2 = u2 - r2 * 10;
    bool has2 = (u2 < 700);
    const unsigned short* base = Bmap + (size_t)h0 * PLANE;
    size_t o0 = (size_t)(64 * by + r0) * ST + 64 * bx + 24 + 8 * k0;
    size_t o1 = (size_t)(64 * by + r1) * ST + 64 * bx + 24 + 8 * k1;
    size_t o2 = (size_t)(64 * by + r2) * ST + 64 * bx + 24 + 8 * k2;

    *(uint4*)&tile[0][r0][8 * k0] = *(const uint4*)(base + o0);
    *(uint4*)&tile[0][r1][8 * k1] = *(const uint4*)(base + o1);
    if (has2) *(uint4*)&tile[0][r2][8 * k2] = *(const uint4*)(base + o2);
    uint4 s0 = *(const uint4*)(base + PLANE + o0);
    uint4 s1 = *(const uint4*)(base + PLANE + o1);
    uint4 s2 = has2 ? *(const uint4*)(base + PLANE + o2) : uint4{0, 0, 0, 0};

    float acc[4][4] = {};
    for (int hh = 0; hh < 5; ++hh) {
        int cur = hh & 1;
        __syncthreads();
        if (hh < 4) {
            *(uint4*)&tile[cur ^ 1][r0][8 * k0] = s0;
            *(uint4*)&tile[cur ^ 1][r1][8 * k1] = s1;
            if (has2) *(uint4*)&tile[cur ^ 1][r2][8 * k2] = s2;
            if (hh < 3) {
                const unsigned short* nb = base + (size_t)(hh + 2) * PLANE;
                s0 = *(const uint4*)(nb + o0);
                s1 = *(const uint4*)(nb + o1);
                if (has2) s2 = *(const uint4*)(nb + o2);
            }
        }
        h2 we[7][4], wo[7][4];
        {
            const uint4* wv = (const uint4*)Wq + (size_t)(h0 + hh) * 14;
#pragma unroll
            for (int di = 0; di < 7; ++di) {
                uint4 a = wv[di];
                we[di][0] = __builtin_bit_cast(h2, a.x);
                we[di][1] = __builtin_bit_cast(h2, a.y);
                we[di][2] = __builtin_bit_cast(h2, a.z);
                we[di][3] = __builtin_bit_cast(h2, a.w);
                uint4 c = wv[7 + di];
                wo[di][0] = __builtin_bit_cast(h2, c.x);
                wo[di][1] = __builtin_bit_cast(h2, c.y);
                wo[di][2] = __builtin_bit_cast(h2, c.z);
                wo[di][3] = __builtin_bit_cast(h2, c.w);
            }
        }
#pragma unroll
        for (int r = 0; r < 10; ++r) {
            const unsigned int* trow = (const unsigned int*)&tile[cur][4 * ly + r][0];
            int mb = 2 * lx + 2;
            uint2 da = *(const uint2*)&trow[mb];
            uint2 db = *(const uint2*)&trow[mb + 2];
            uint2 dc = *(const uint2*)&trow[mb + 4];
            h2 q0 = __builtin_bit_cast(h2, da.x), q1 = __builtin_bit_cast(h2, da.y);
            h2 q2 = __builtin_bit_cast(h2, db.x), q3 = __builtin_bit_cast(h2, db.y);
            h2 q4 = __builtin_bit_cast(h2, dc.x), q5 = __builtin_bit_cast(h2, dc.y);
#pragma unroll
            for (int rr = 0; rr < 4; ++rr) {
                int di = r - rr;
                if (di < 0 || di > 6) continue;
                acc[rr][0] = __builtin_amdgcn_fdot2(q0, wo[di][0],
                             __builtin_amdgcn_fdot2(q1, wo[di][1],
                             __builtin_amdgcn_fdot2(q2, wo[di][2],
                             __builtin_amdgcn_fdot2(q3, wo[di][3], acc[rr][0], false), false), false), false);
                acc[rr][1] = __builtin_amdgcn_fdot2(q1, we[di][0],
                             __builtin_amdgcn_fdot2(q2, we[di][1],
                             __builtin_amdgcn_fdot2(q3, we[di][2],
                             __builtin_amdgcn_fdot2(q4, we[di][3], acc[rr][1], false), false), false), false);
                acc[rr][2] = __builtin_amdgcn_fdot2(q1, wo[di][0],
                             __builtin_amdgcn_fdot2(q2, wo[di][1],
                             __builtin_amdgcn_fdot2(q3, wo[di][2],
                             __builtin_amdgcn_fdot2(q4, wo[di][3], acc[rr][2], false), false), false), false);
                acc[rr][3] = __builtin_amdgcn_fdot2(q2, we[di][0],
                             __builtin_amdgcn_fdot2(q3, we[di][1],
                             __builtin_amdgcn_fdot2(q4, we[di][2],
                             __builtin_amdgcn_fdot2(q5, we[di][3], acc[rr][3], false), false), false), false);
            }
        }
    }
    int j = 64 * bx + 4 * lx;
    if (j < 800) {
#pragma unroll
        for (int rr = 0; rr < 4; ++rr) {
            int i = 64 * by + 4 * ly + rr;
            if (i < 800) {
                unsigned short st[4];
#pragma unroll
                for (int cc = 0; cc < 4; ++cc) st[cc] = f16b(acc[rr][cc]);
                *(ushort4*)&CpH[(size_t)zc * 640000 + (size_t)i * 800 + j] =
                    *(ushort4*)st;
            }
        }
    }
}

// ---------------- Kernel 3b: reduce fp16 partials + bias + bn2 -> f32 C ----------------
__global__ __launch_bounds__(256) void kreduce(const unsigned short* __restrict__ CpH,
                                               const float* __restrict__ b2,
                                               const float* __restrict__ g2,
                                               const float* __restrict__ bb2,
                                               const float* __restrict__ m2,
                                               const float* __restrict__ v2,
                                               float* __restrict__ C) {
    int idx = blockIdx.x * 256 + threadIdx.x;
    if (idx >= 80000) return;
    float s2 = g2[0] * rsqrtf(v2[0] + EPS);
    float t2 = bb2[0] - m2[0] * s2;
    float bias = b2[0];
    float s[8] = {0.f, 0.f, 0.f, 0.f, 0.f, 0.f, 0.f, 0.f};
#pragma unroll
    for (int z = 0; z < 10; z++) {
        uint4 v = ((const uint4*)(CpH + (size_t)z * 640000))[idx];
        h2 p0 = __builtin_bit_cast(h2, v.x), p1 = __builtin_bit_cast(h2, v.y);
        h2 p2 = __builtin_bit_cast(h2, v.z), p3 = __builtin_bit_cast(h2, v.w);
        s[0] += (float)p0[0]; s[1] += (float)p0[1];
        s[2] += (float)p1[0]; s[3] += (float)p1[1];
        s[4] += (float)p2[0]; s[5] += (float)p2[1];
        s[6] += (float)p3[0]; s[7] += (float)p3[1];
    }
    float4 oa, ob;
    oa.x = (s[0] + bias) * s2 + t2; oa.y = (s[1] + bias) * s2 + t2;
    oa.z = (s[2] + bias) * s2 + t2; oa.w = (s[3] + bias) * s2 + t2;
    ob.x = (s[4] + bias) * s2 + t2; ob.y = (s[5] + bias) * s2 + t2;
    ob.z = (s[6] + bias) * s2 + t2; ob.w = (s[7] + bias) * s2 + t2;
    ((float4*)C)[idx * 2] = oa;
    ((float4*)C)[idx * 2 + 1] = ob;
}

// ---------------- Kernel 4: 9x9/9 maxpool with pad 4 -> yhat (89x89) ----------------
__global__ __launch_bounds__(256) void kpool(const float* __restrict__ C,
                                             float* __restrict__ yhat) {
    int idx = blockIdx.x * 256 + threadIdx.x;
    if (idx >= 89 * 89) return;
    int oy = idx / 89, ox = idx % 89;
    float mx = -INFINITY;
    int y0 = oy * 9 - 4, x0 = ox * 9 - 4;
    for (int dy = 0; dy < 9; dy++) {
        int y = y0 + dy;
        if (y < 0 || y >= 800) continue;
        for (int dx = 0; dx < 9; dx++) {
            int x = x0 + dx;
            if (x < 0 || x >= 800) continue;
            mx = fmaxf(mx, C[y * 800 + x]);
        }
    }
    yhat[idx] = mx;
}

// ---------------- Kernel 5: mean/var -> Q -> phat -> gelu ----------------
__global__ __launch_bounds__(256) void kfinal(const float* __restrict__ yhat,
                                              const float* __restrict__ gamma,
                                              float* __restrict__ out) {
    const int N = 89 * 89;
    __shared__ float sA[4], sB[4];
    int tid = threadIdx.x;
    int wid = tid >> 6, lane = tid & 63;
    float s = 0.f, ss = 0.f;
    for (int i = tid; i < N; i += 256) {
        float y = yhat[i];
        s += y;
        ss = fmaf(y, y, ss);
    }
    for (int off = 32; off; off >>= 1) {
        s += __shfl_down(s, off);
        ss += __shfl_down(ss, off);
    }
    if (lane == 0) { sA[wid] = s; sB[wid] = ss; }
    __syncthreads();
    float S = sA[0] + sA[1] + sA[2] + sA[3];
    float SS = sB[0] + sB[1] + sB[2] + sB[3];
    float mu = S / (float)N;
    float var = (SS - S * S / (float)N) / (float)(N - 1);
    float thr = mu + gamma[0] * var;
    __syncthreads();
    float q = 0.f, c = 0.f;
    for (int i = tid; i < N; i += 256) {
        float d = yhat[i] - thr;
        if (d > 0.f) { q += d; c += 1.f; }
    }
    for (int off = 32; off; off >>= 1) {
        q += __shfl_down(q, off);
        c += __shfl_down(c, off);
    }
    if (lane == 0) { sA[wid] = q; sB[wid] = c; }
    __syncthreads();
    if (tid == 0) {
        float Q = sA[0] + sA[1] + sA[2] + sA[3];
        float Cnt = sB[0] + sB[1] + sB[2] + sB[3];
        float phat = Q / (Cnt + 1.f);
        out[0] = 0.5f * phat * (1.f + erff(phat * 0.70710678118654752f));
    }
}

extern "C" void kernel_launch(void* const* d_in, const int* in_sizes, int n_in,
                              void* d_out, int out_size, void* d_ws, size_t ws_size,
                              hipStream_t stream) {
    const float* z0   = (const float*)d_in[0];
    const float* z1   = (const float*)d_in[1];
    const float* Wemb = (const float*)d_in[2];
    const float* bemb = (const float*)d_in[3];
    const float* W1   = (const float*)d_in[4];
    const float* b1   = (const float*)d_in[5];
    const float* bn1g = (const float*)d_in[6];
    const float* bn1b = (const float*)d_in[7];
    const float* bn1m = (const float*)d_in[8];
    const float* bn1v = (const float*)d_in[9];
    const float* W2   = (const float*)d_in[10];
    const float* b2   = (const float*)d_in[11];
    const float* bn2g = (const float*)d_in[12];
    const float* bn2b = (const float*)d_in[13];
    const float* bn2m = (const float*)d_in[14];
    const float* bn2v = (const float*)d_in[15];
    const float* gam  = (const float*)d_in[16];

    unsigned short* e0h  = (unsigned short*)d_ws;               // 800 x 112 fp16
    unsigned short* e1h  = e0h + 89600;
    unsigned short* Bh   = e1h + 89600;                         // 16,384 fp16
    unsigned short* Wq   = Bh + 16384;                          // 5,600 fp16
    unsigned short* Bmap = Wq + 5600;                           // 50 x PLANE fp16
    unsigned short* CpH  = Bmap + (size_t)50 * PLANE;           // 10 x 640,000 fp16
    float* Cbuf = (float*)Bmap;                                 // alias (Bmap dead after kconv)
    float* yhat = Cbuf + 640000;
    float* out  = (float*)d_out;

    kprep<<<1236, 256, 0, stream>>>(z0, z1, Wemb, bemb, e0h, e1h, W1, Bh,
                                    Bmap, W2, Wq);
    dim3 gi(100, 25);
    kinter<<<gi, 256, 0, stream>>>(e0h, e1h, Bh, b1, bn1g, bn1b, bn1m, bn1v, Bmap);
    dim3 gc(13, 13, 10);
    kconv<<<gc, 256, 0, stream>>>(Bmap, Wq, CpH);
    kreduce<<<(80000 + 255) / 256, 256, 0, stream>>>(CpH, b2, bn2g, bn2b, bn2m, bn2v, Cbuf);
    kpool<<<(89 * 89 + 255) / 256, 256, 0, stream>>>(Cbuf, yhat);
    kfinal<<<1, 256, 0, stream>>>(yhat, gam, out);
}

// Round 13
// 140.090 us; speedup vs baseline: 2.0032x; 1.0582x over previous
//
#include <hip/hip_runtime.h>
#include <hip/hip_bf16.h>
#include <math.h>

#define EPS 1e-5f
#define ST 896                   // padded Bmap row stride (fp16 elems), 64B-multiple
#define PLANE (896 * 806)        // padded plane elems (3+800+3 rows)
#define PLANE4 (PLANE / 8)       // uint4 per plane = 90272

typedef _Float16 f16x8 __attribute__((ext_vector_type(8)));
typedef _Float16 h2 __attribute__((ext_vector_type(2)));
typedef float f32x4 __attribute__((ext_vector_type(4)));

__device__ __forceinline__ float elu_f(float x) {
    return x > 0.f ? x : __expf(x) - 1.f;
}
__device__ __forceinline__ unsigned short f16b(float x) {
    return __builtin_bit_cast(unsigned short, (_Float16)x);
}

// ---- Merged prep ----
// b<100:      kembed via MFMA (16 z-rows/block, e fp16 rows padded to 112)
// 100..163:   kprepW (W1 -> fp16 B-fragments, K=256 split-K layout)
// 164..1232:  kzero  (halo borders of padded Bmap)
// 1233..1235: W2pack (dual-alignment fp16 weight quads)
__global__ __launch_bounds__(256) void kprep(const float* __restrict__ z0,
                                             const float* __restrict__ z1,
                                             const float* __restrict__ Wemb,
                                             const float* __restrict__ bemb,
                                             unsigned short* __restrict__ e0h,
                                             unsigned short* __restrict__ e1h,
                                             const float* __restrict__ W1,
                                             unsigned short* __restrict__ Bh,
                                             unsigned short* __restrict__ Bmap,
                                             const float* __restrict__ W2,
                                             unsigned short* __restrict__ Wq) {
    __shared__ unsigned short zls[16][1032];   // 16 z-rows fp16, padded stride
    int b = blockIdx.x;
    int tid = threadIdx.x;
    if (b < 100) {
        // ---- kembed MFMA: e[m][d] = elu(z[m][:] . Wemb[d][:] + bemb[d]) ----
        int src = b & 1;
        int rowbase = (b >> 1) * 16;
        const float* z = src ? z1 : z0;
        unsigned short* e = src ? e1h : e0h;
        const float4* zr4 = (const float4*)(z + rowbase * 1024);
        for (int idx = tid; idx < 4096; idx += 256) {
            int r = idx >> 8, c = idx & 255;
            float4 v = zr4[idx];
            unsigned int p0 = __builtin_bit_cast(unsigned int,
                __builtin_amdgcn_cvt_pkrtz(v.x, v.y));
            unsigned int p1 = __builtin_bit_cast(unsigned int,
                __builtin_amdgcn_cvt_pkrtz(v.z, v.w));
            uint2 pv = {p0, p1};
            *(uint2*)&zls[r][c * 4] = pv;
        }
        __syncthreads();
        int lane = tid & 63, wid = tid >> 6;
        int g = lane >> 4, rl = lane & 15;
        int mf0 = wid * 2;
        int nfrag = (wid < 3) ? 2 : 1;      // 7 d-frags over 4 waves
        f32x4 acc[2] = {};
        for (int ks = 0; ks < 32; ++ks) {
            f16x8 bz = *(const f16x8*)&zls[rl][ks * 32 + g * 8];
#pragma unroll
            for (int q = 0; q < 2; ++q) {
                if (q < nfrag) {
                    int d = (mf0 + q) * 16 + rl;
                    d = d > 99 ? 99 : d;
                    const float* wp = Wemb + d * 1024 + ks * 32 + g * 8;
                    float4 w0 = *(const float4*)wp;
                    float4 w1 = *(const float4*)(wp + 4);
                    uint4 au;
                    au.x = __builtin_bit_cast(unsigned int,
                        __builtin_amdgcn_cvt_pkrtz(w0.x, w0.y));
                    au.y = __builtin_bit_cast(unsigned int,
                        __builtin_amdgcn_cvt_pkrtz(w0.z, w0.w));
                    au.z = __builtin_bit_cast(unsigned int,
                        __builtin_amdgcn_cvt_pkrtz(w1.x, w1.y));
                    au.w = __builtin_bit_cast(unsigned int,
                        __builtin_amdgcn_cvt_pkrtz(w1.z, w1.w));
                    f16x8 a = __builtin_bit_cast(f16x8, au);
                    acc[q] = __builtin_amdgcn_mfma_f32_16x16x32_f16(a, bz, acc[q], 0, 0, 0);
                }
            }
        }
#pragma unroll
        for (int q = 0; q < 2; ++q) {
            if (q < nfrag) {
                int dbase = (mf0 + q) * 16 + g * 4;
                int zr = rowbase + rl;
                unsigned short o[4];
#pragma unroll
                for (int r = 0; r < 4; ++r) {
                    int d = dbase + r;
                    float be = bemb[d > 99 ? 99 : d];
                    float x = elu_f(acc[q][r] + be);
                    o[r] = (d < 100) ? f16b(x) : (unsigned short)0;
                }
                *(ushort4*)&e[zr * 112 + dbase] = *(ushort4*)o;
            }
        }
    } else if (b < 164) {
        // ---- kprepW: fp16 B-fragments; K=256: k<128 dif(d=k), k>=128 mul(d=k-128) ----
        int idx = (b - 100) * 256 + tid;     // 0..16383
        int i = idx & 7;
        int lane = (idx >> 3) & 63;
        int hf = (idx >> 9) & 3;
        int ks = idx >> 11;                  // 0..7
        int h = hf * 16 + (lane & 15);
        int k = ks * 32 + (lane >> 4) * 8 + i;
        int term = k >> 7;
        int d = k & 127;
        float val = (d < 100 && h < 50) ? W1[h * 200 + term * 100 + d] : 0.f;
        Bh[idx] = f16b(val);
    } else if (b < 1233) {
        // ---- kzero: halo borders of padded Bmap (uint4) ----
        int idx = (b - 164) * 256 + tid;
        if (idx < 273600) {
            int h = idx / 5472, q = idx % 5472;
            int row, colv;
            if (q < 672) {
                int rr = q / 112;
                colv = q - rr * 112;
                row = rr < 3 ? rr : 800 + rr;
            } else {
                int q2 = q - 672;
                row = 3 + q2 / 6;
                int s = q2 % 6;
                colv = (s == 0) ? 3 : 103 + s;
            }
            uint4 zz = {0, 0, 0, 0};
            ((uint4*)Bmap)[(size_t)h * PLANE4 + row * 112 + colv] = zz;
        }
    } else {
        // ---- W2 pack: dual-alignment fp16 weight quads for dot2 conv ----
        int idx = (b - 1233) * 256 + tid;
        if (idx < 700) {
            int h = idx / 14, rem = idx % 14;
            int lay = rem / 7, di = rem % 7;
            const float* wsrc = W2 + h * 49 + di * 7;
            unsigned short wf[8];
            if (lay == 0) {
#pragma unroll
                for (int t = 0; t < 7; t++) wf[t] = f16b(wsrc[t]);
                wf[7] = 0;
            } else {
                wf[0] = 0;
#pragma unroll
                for (int t = 0; t < 7; t++) wf[t + 1] = f16b(wsrc[t]);
            }
            *(uint4*)&Wq[idx * 8] = *(uint4*)wf;
        }
    }
}

// ---------------- Kernel 2: interaction GEMM via MFMA (fp16, split-K 256) ----------------
// grid (100,25), 256 thr = 4 waves. Tile 8 i x 32 j. fp16 e in LDS (stride 120).
__global__ __launch_bounds__(256) void kinter(const unsigned short* __restrict__ e0h,
                                              const unsigned short* __restrict__ e1h,
                                              const unsigned short* __restrict__ Bh,
                                              const float* __restrict__ b1,
                                              const float* __restrict__ g1,
                                              const float* __restrict__ bb1,
                                              const float* __restrict__ m1,
                                              const float* __restrict__ v1,
                                              unsigned short* __restrict__ Bmap) {
    __shared__ unsigned short e0s[8][120];
    __shared__ unsigned short e1s[32][120];
    int i0 = blockIdx.x * 8, j0 = blockIdx.y * 32;
    int tid = threadIdx.x;
    for (int idx = tid; idx < 600; idx += 256) {
        int r = idx / 15, c = idx % 15;
        uint4 v = {0, 0, 0, 0};
        if (c < 14)
            v = (r < 8) ? *(const uint4*)(e0h + (i0 + r) * 112 + c * 8)
                        : *(const uint4*)(e1h + (j0 + r - 8) * 112 + c * 8);
        if (r < 8) *(uint4*)&e0s[r][c * 8] = v;
        else *(uint4*)&e1s[r - 8][c * 8] = v;
    }
    __syncthreads();

    int lane = tid & 63;
    int wid = tid >> 6;
    int g = lane >> 4;
    int jrow = lane & 15;

    f32x4 acc[2][2][4] = {};

#pragma unroll
    for (int ks = 0; ks < 8; ++ks) {
        f16x8 b[4];
#pragma unroll
        for (int hf = 0; hf < 4; ++hf) {
            int fidx = ((ks * 4 + hf) * 64 + lane) * 8;
            b[hf] = __builtin_bit_cast(f16x8, *(const uint4*)(Bh + fidx));
        }
        int d0 = (ks & 3) * 32 + g * 8;
        d0 = d0 > 112 ? 112 : d0;
        f16x8 x0v[2];
        x0v[0] = *(const f16x8*)&e0s[wid * 2 + 0][d0];
        x0v[1] = *(const f16x8*)&e0s[wid * 2 + 1][d0];
#pragma unroll
        for (int jf = 0; jf < 2; ++jf) {
            f16x8 x1 = *(const f16x8*)&e1s[jf * 16 + jrow][d0];
#pragma unroll
            for (int fl = 0; fl < 2; ++fl) {
                f16x8 a;
                if (ks < 4) {
                    f16x8 dd = x0v[fl] - x1;
                    uint4 u = __builtin_bit_cast(uint4, dd);
                    u.x &= 0x7FFF7FFFu; u.y &= 0x7FFF7FFFu;
                    u.z &= 0x7FFF7FFFu; u.w &= 0x7FFF7FFFu;
                    a = __builtin_bit_cast(f16x8, u);
                } else {
                    a = x0v[fl] * x1;
                }
#pragma unroll
                for (int hf = 0; hf < 4; ++hf) {
                    acc[fl][jf][hf] = __builtin_amdgcn_mfma_f32_16x16x32_f16(
                        a, b[hf], acc[fl][jf][hf], 0, 0, 0);
                }
            }
        }
    }

    int hl = lane & 15;
#pragma unroll
    for (int hf = 0; hf < 4; ++hf) {
        int h = hf * 16 + hl;
        bool ok = h < 50;
        int hc = ok ? h : 0;
        float bnb = b1[hc];
        float sc = g1[hc] * rsqrtf(v1[hc] + EPS);
        float off = bb1[hc] - m1[hc] * sc;
#pragma unroll
        for (int fl = 0; fl < 2; ++fl) {
            int i = i0 + wid * 2 + fl;
#pragma unroll
            for (int jf = 0; jf < 2; ++jf) {
                int j = j0 + jf * 16 + g * 4;
                f32x4 a = acc[fl][jf][hf];
                unsigned short o[4];
#pragma unroll
                for (int r = 0; r < 4; ++r) {
                    float x = a[r] + bnb;
                    x = elu_f(x);
                    x = fmaf(x, sc, off);
                    x = elu_f(x);
                    o[r] = f16b(x);
                }
                if (ok) {
                    *(ushort4*)&Bmap[(size_t)h * PLANE + (size_t)(i + 3) * ST + (j + 32)] =
                        *(ushort4*)o;
                }
            }
        }
    }
}

// ---------------- Kernel 3: 7x7 conv via v_dot2_f32_f16, fp16 LDS, dbuf ----------------
// 1D grid 1690 with XCD-chunked bijective swizzle (q=211, r=2): adjacent tiles
// (sharing halo cache lines) land on the SAME XCD's L2.
__global__ __launch_bounds__(256) void kconv(const unsigned short* __restrict__ Bmap,
                                             const unsigned short* __restrict__ Wq,
                                             unsigned short* __restrict__ CpH) {
    __shared__ unsigned short tile[2][70][80];
    int orig = blockIdx.x;
    int xcd = orig & 7, pos = orig >> 3;
    int t = (xcd < 2) ? xcd * 212 + pos : 424 + (xcd - 2) * 211 + pos;
    int bx = t % 13;
    int t2 = t / 13;
    int by = t2 % 13, zc = t2 / 13;
    int h0 = zc * 5;
    int tid = threadIdx.x;
    int lx = tid & 15, ly = tid >> 4;

    int u0 = tid, u1 = tid + 256, u2 = tid + 512;
    int r0 = u0 / 10, k0 = u0 - r0 * 10;
    int r1 = u1 / 10, k1 = u1 - r1 * 10;
    int r2 = u2 / 10, k2 = u2 - r2 * 10;
    bool has2 = (u2 < 700);
    const unsigned short* base = Bmap + (size_t)h0 * PLANE;
    size_t o0 = (size_t)(64 * by + r0) * ST + 64 * bx + 24 + 8 * k0;
    size_t o1 = (size_t)(64 * by + r1) * ST + 64 * bx + 24 + 8 * k1;
    size_t o2 = (size_t)(64 * by + r2) * ST + 64 * bx + 24 + 8 * k2;

    *(uint4*)&tile[0][r0][8 * k0] = *(const uint4*)(base + o0);
    *(uint4*)&tile[0][r1][8 * k1] = *(const uint4*)(base + o1);
    if (has2) *(uint4*)&tile[0][r2][8 * k2] = *(const uint4*)(base + o2);
    uint4 s0 = *(const uint4*)(base + PLANE + o0);
    uint4 s1 = *(const uint4*)(base + PLANE + o1);
    uint4 s2 = has2 ? *(const uint4*)(base + PLANE + o2) : uint4{0, 0, 0, 0};

    float acc[4][4] = {};
    for (int hh = 0; hh < 5; ++hh) {
        int cur = hh & 1;
        __syncthreads();
        if (hh < 4) {
            *(uint4*)&tile[cur ^ 1][r0][8 * k0] = s0;
            *(uint4*)&tile[cur ^ 1][r1][8 * k1] = s1;
            if (has2) *(uint4*)&tile[cur ^ 1][r2][8 * k2] = s2;
            if (hh < 3) {
                const unsigned short* nb = base + (size_t)(hh + 2) * PLANE;
                s0 = *(const uint4*)(nb + o0);
                s1 = *(const uint4*)(nb + o1);
                if (has2) s2 = *(const uint4*)(nb + o2);
            }
        }
        h2 we[7][4], wo[7][4];
        {
            const uint4* wv = (const uint4*)Wq + (size_t)(h0 + hh) * 14;
#pragma unroll
            for (int di = 0; di < 7; ++di) {
                uint4 a = wv[di];
                we[di][0] = __builtin_bit_cast(h2, a.x);
                we[di][1] = __builtin_bit_cast(h2, a.y);
                we[di][2] = __builtin_bit_cast(h2, a.z);
                we[di][3] = __builtin_bit_cast(h2, a.w);
                uint4 c = wv[7 + di];
                wo[di][0] = __builtin_bit_cast(h2, c.x);
                wo[di][1] = __builtin_bit_cast(h2, c.y);
                wo[di][2] = __builtin_bit_cast(h2, c.z);
                wo[di][3] = __builtin_bit_cast(h2, c.w);
            }
        }
#pragma unroll
        for (int r = 0; r < 10; ++r) {
            const unsigned int* trow = (const unsigned int*)&tile[cur][4 * ly + r][0];
            int mb = 2 * lx + 2;
            uint2 da = *(const uint2*)&trow[mb];
            uint2 db = *(const uint2*)&trow[mb + 2];
            uint2 dc = *(const uint2*)&trow[mb + 4];
            h2 q0 = __builtin_bit_cast(h2, da.x), q1 = __builtin_bit_cast(h2, da.y);
            h2 q2 = __builtin_bit_cast(h2, db.x), q3 = __builtin_bit_cast(h2, db.y);
            h2 q4 = __builtin_bit_cast(h2, dc.x), q5 = __builtin_bit_cast(h2, dc.y);
#pragma unroll
            for (int rr = 0; rr < 4; ++rr) {
                int di = r - rr;
                if (di < 0 || di > 6) continue;
                acc[rr][0] = __builtin_amdgcn_fdot2(q0, wo[di][0],
                             __builtin_amdgcn_fdot2(q1, wo[di][1],
                             __builtin_amdgcn_fdot2(q2, wo[di][2],
                             __builtin_amdgcn_fdot2(q3, wo[di][3], acc[rr][0], false), false), false), false);
                acc[rr][1] = __builtin_amdgcn_fdot2(q1, we[di][0],
                             __builtin_amdgcn_fdot2(q2, we[di][1],
                             __builtin_amdgcn_fdot2(q3, we[di][2],
                             __builtin_amdgcn_fdot2(q4, we[di][3], acc[rr][1], false), false), false), false);
                acc[rr][2] = __builtin_amdgcn_fdot2(q1, wo[di][0],
                             __builtin_amdgcn_fdot2(q2, wo[di][1],
                             __builtin_amdgcn_fdot2(q3, wo[di][2],
                             __builtin_amdgcn_fdot2(q4, wo[di][3], acc[rr][2], false), false), false), false);
                acc[rr][3] = __builtin_amdgcn_fdot2(q2, we[di][0],
                             __builtin_amdgcn_fdot2(q3, we[di][1],
                             __builtin_amdgcn_fdot2(q4, we[di][2],
                             __builtin_amdgcn_fdot2(q5, we[di][3], acc[rr][3], false), false), false), false);
            }
        }
    }
    int j = 64 * bx + 4 * lx;
    if (j < 800) {
#pragma unroll
        for (int rr = 0; rr < 4; ++rr) {
            int i = 64 * by + 4 * ly + rr;
            if (i < 800) {
                unsigned short st[4];
#pragma unroll
                for (int cc = 0; cc < 4; ++cc) st[cc] = f16b(acc[rr][cc]);
                *(ushort4*)&CpH[(size_t)zc * 640000 + (size_t)i * 800 + j] =
                    *(ushort4*)st;
            }
        }
    }
}

// ---------------- Kernel 3b: reduce fp16 partials + bias + bn2 -> f32 C ----------------
__global__ __launch_bounds__(256) void kreduce(const unsigned short* __restrict__ CpH,
                                               const float* __restrict__ b2,
                                               const float* __restrict__ g2,
                                               const float* __restrict__ bb2,
                                               const float* __restrict__ m2,
                                               const float* __restrict__ v2,
                                               float* __restrict__ C) {
    int idx = blockIdx.x * 256 + threadIdx.x;
    if (idx >= 80000) return;
    float s2 = g2[0] * rsqrtf(v2[0] + EPS);
    float t2 = bb2[0] - m2[0] * s2;
    float bias = b2[0];
    float s[8] = {0.f, 0.f, 0.f, 0.f, 0.f, 0.f, 0.f, 0.f};
#pragma unroll
    for (int z = 0; z < 10; z++) {
        uint4 v = ((const uint4*)(CpH + (size_t)z * 640000))[idx];
        h2 p0 = __builtin_bit_cast(h2, v.x), p1 = __builtin_bit_cast(h2, v.y);
        h2 p2 = __builtin_bit_cast(h2, v.z), p3 = __builtin_bit_cast(h2, v.w);
        s[0] += (float)p0[0]; s[1] += (float)p0[1];
        s[2] += (float)p1[0]; s[3] += (float)p1[1];
        s[4] += (float)p2[0]; s[5] += (float)p2[1];
        s[6] += (float)p3[0]; s[7] += (float)p3[1];
    }
    float4 oa, ob;
    oa.x = (s[0] + bias) * s2 + t2; oa.y = (s[1] + bias) * s2 + t2;
    oa.z = (s[2] + bias) * s2 + t2; oa.w = (s[3] + bias) * s2 + t2;
    ob.x = (s[4] + bias) * s2 + t2; ob.y = (s[5] + bias) * s2 + t2;
    ob.z = (s[6] + bias) * s2 + t2; ob.w = (s[7] + bias) * s2 + t2;
    ((float4*)C)[idx * 2] = oa;
    ((float4*)C)[idx * 2 + 1] = ob;
}

// ---------------- Kernel 4: 9x9/9 maxpool with pad 4 -> yhat (89x89) ----------------
__global__ __launch_bounds__(256) void kpool(const float* __restrict__ C,
                                             float* __restrict__ yhat) {
    int idx = blockIdx.x * 256 + threadIdx.x;
    if (idx >= 89 * 89) return;
    int oy = idx / 89, ox = idx % 89;
    float mx = -INFINITY;
    int y0 = oy * 9 - 4, x0 = ox * 9 - 4;
    for (int dy = 0; dy < 9; dy++) {
        int y = y0 + dy;
        if (y < 0 || y >= 800) continue;
        for (int dx = 0; dx < 9; dx++) {
            int x = x0 + dx;
            if (x < 0 || x >= 800) continue;
            mx = fmaxf(mx, C[y * 800 + x]);
        }
    }
    yhat[idx] = mx;
}

// ---------------- Kernel 5: mean/var -> Q -> phat -> gelu ----------------
__global__ __launch_bounds__(256) void kfinal(const float* __restrict__ yhat,
                                              const float* __restrict__ gamma,
                                              float* __restrict__ out) {
    const int N = 89 * 89;
    __shared__ float sA[4], sB[4];
    int tid = threadIdx.x;
    int wid = tid >> 6, lane = tid & 63;
    float s = 0.f, ss = 0.f;
    for (int i = tid; i < N; i += 256) {
        float y = yhat[i];
        s += y;
        ss = fmaf(y, y, ss);
    }
    for (int off = 32; off; off >>= 1) {
        s += __shfl_down(s, off);
        ss += __shfl_down(ss, off);
    }
    if (lane == 0) { sA[wid] = s; sB[wid] = ss; }
    __syncthreads();
    float S = sA[0] + sA[1] + sA[2] + sA[3];
    float SS = sB[0] + sB[1] + sB[2] + sB[3];
    float mu = S / (float)N;
    float var = (SS - S * S / (float)N) / (float)(N - 1);
    float thr = mu + gamma[0] * var;
    __syncthreads();
    float q = 0.f, c = 0.f;
    for (int i = tid; i < N; i += 256) {
        float d = yhat[i] - thr;
        if (d > 0.f) { q += d; c += 1.f; }
    }
    for (int off = 32; off; off >>= 1) {
        q += __shfl_down(q, off);
        c += __shfl_down(c, off);
    }
    if (lane == 0) { sA[wid] = q; sB[wid] = c; }
    __syncthreads();
    if (tid == 0) {
        float Q = sA[0] + sA[1] + sA[2] + sA[3];
        float Cnt = sB[0] + sB[1] + sB[2] + sB[3];
        float phat = Q / (Cnt + 1.f);
        out[0] = 0.5f * phat * (1.f + erff(phat * 0.70710678118654752f));
    }
}

extern "C" void kernel_launch(void* const* d_in, const int* in_sizes, int n_in,
                              void* d_out, int out_size, void* d_ws, size_t ws_size,
                              hipStream_t stream) {
    const float* z0   = (const float*)d_in[0];
    const float* z1   = (const float*)d_in[1];
    const float* Wemb = (const float*)d_in[2];
    const float* bemb = (const float*)d_in[3];
    const float* W1   = (const float*)d_in[4];
    const float* b1   = (const float*)d_in[5];
    const float* bn1g = (const float*)d_in[6];
    const float* bn1b = (const float*)d_in[7];
    const float* bn1m = (const float*)d_in[8];
    const float* bn1v = (const float*)d_in[9];
    const float* W2   = (const float*)d_in[10];
    const float* b2   = (const float*)d_in[11];
    const float* bn2g = (const float*)d_in[12];
    const float* bn2b = (const float*)d_in[13];
    const float* bn2m = (const float*)d_in[14];
    const float* bn2v = (const float*)d_in[15];
    const float* gam  = (const float*)d_in[16];

    unsigned short* e0h  = (unsigned short*)d_ws;               // 800 x 112 fp16
    unsigned short* e1h  = e0h + 89600;
    unsigned short* Bh   = e1h + 89600;                         // 16,384 fp16
    unsigned short* Wq   = Bh + 16384;                          // 5,600 fp16
    unsigned short* Bmap = Wq + 5600;                           // 50 x PLANE fp16
    unsigned short* CpH  = Bmap + (size_t)50 * PLANE;           // 10 x 640,000 fp16
    float* Cbuf = (float*)Bmap;                                 // alias (Bmap dead after kconv)
    float* yhat = Cbuf + 640000;
    float* out  = (float*)d_out;

    kprep<<<1236, 256, 0, stream>>>(z0, z1, Wemb, bemb, e0h, e1h, W1, Bh,
                                    Bmap, W2, Wq);
    dim3 gi(100, 25);
    kinter<<<gi, 256, 0, stream>>>(e0h, e1h, Bh, b1, bn1g, bn1b, bn1m, bn1v, Bmap);
    kconv<<<1690, 256, 0, stream>>>(Bmap, Wq, CpH);
    kreduce<<<(80000 + 255) / 256, 256, 0, stream>>>(CpH, b2, bn2g, bn2b, bn2m, bn2v, Cbuf);
    kpool<<<(89 * 89 + 255) / 256, 256, 0, stream>>>(Cbuf, yhat);
    kfinal<<<1, 256, 0, stream>>>(yhat, gam, out);
}